// Round 4
// baseline (387.567 us; speedup 1.0000x reference)
//
#include <hip/hip_runtime.h>

typedef unsigned short u16;
typedef __attribute__((ext_vector_type(8))) short short8;
typedef __attribute__((ext_vector_type(8))) _Float16 h8;
typedef __attribute__((ext_vector_type(4))) float f32x4;

// ---- bf16 <-> f32 bit helpers ----
__device__ __forceinline__ float b2f(u16 u) {
    return __uint_as_float(((unsigned int)u) << 16);
}
__device__ __forceinline__ u16 f2b(float f) {
    unsigned int x = __float_as_uint(f);
    return (u16)((x + 0x7FFFu + ((x >> 16) & 1u)) >> 16);   // RNE
}
__device__ __forceinline__ float ldf(const void* p, size_t i, bool f32) {
    return f32 ? ((const float*)p)[i] : b2f(((const u16*)p)[i]);
}
__device__ __forceinline__ void stf(void* p, size_t i, bool f32, float v) {
    if (f32) ((float*)p)[i] = v; else ((u16*)p)[i] = f2b(v);
}
// raw v_exp_f32: computes 2^x in one trans op (no log2e pre-mul)
__device__ __forceinline__ float ex2(float x) {
    float r; asm("v_exp_f32 %0, %1" : "=v"(r) : "v"(x)); return r;
}
__device__ __forceinline__ float rsqf(float x) {
    float r; asm("v_rsq_f32 %0, %1" : "=v"(r) : "v"(x)); return r;
}

// async global -> LDS, 16 B per lane (dest = wave-uniform base + lane*16)
__device__ __forceinline__ void ldsld16(const void* g, void* l) {
    __builtin_amdgcn_global_load_lds(
        (const __attribute__((address_space(1))) unsigned int*)g,
        (__attribute__((address_space(3))) unsigned int*)l, 16, 0, 0);
}

// ---------------------------------------------------------------------------
// dtype probe (evidence: flag=1/f32 on this harness; keep robust)
// ---------------------------------------------------------------------------
__global__ void detect_f32(const u16* __restrict__ q, int* __restrict__ flag) {
    __shared__ int cw, cz;
    if (threadIdx.x == 0) { cw = 0; cz = 0; }
    __syncthreads();
    int w = 0, z = 0;
    for (int i = threadIdx.x; i < 4096; i += 256) {
        u16 u = q[i];
        int e = (u >> 7) & 0xFF;
        if (e >= 0xC8) w++;
        if (((i & 1) == 0) && u == 0) z++;
    }
    atomicAdd(&cw, w); atomicAdd(&cz, z);
    __syncthreads();
    if (threadIdx.x == 0) *flag = (cw > 8 || cz > 1024) ? 1 : 0;
}

// ---------------------------------------------------------------------------
// convert 3 tensors -> bf16 ws in one launch. grid (n/2048, 1, 3)
// ---------------------------------------------------------------------------
__global__ __launch_bounds__(256) void cvt3(
    const void* __restrict__ s0, const void* __restrict__ s1,
    const void* __restrict__ s2, u16* __restrict__ d0, u16* __restrict__ d1,
    u16* __restrict__ d2, int n, const int* __restrict__ flag)
{
    const bool f32 = (*flag) != 0;
    const int z = blockIdx.z;
    const void* src = (z == 0) ? s0 : (z == 1) ? s1 : s2;
    u16* dst = (z == 0) ? d0 : (z == 1) ? d1 : d2;
    const int i = (blockIdx.x * 256 + threadIdx.x) * 8;
    if (i >= n) return;
    short8 o;
    if (f32) {
        const float4* s = (const float4*)((const float*)src + i);
        float4 v0 = s[0], v1 = s[1];
        o[0] = (short)f2b(v0.x); o[1] = (short)f2b(v0.y);
        o[2] = (short)f2b(v0.z); o[3] = (short)f2b(v0.w);
        o[4] = (short)f2b(v1.x); o[5] = (short)f2b(v1.y);
        o[6] = (short)f2b(v1.z); o[7] = (short)f2b(v1.w);
    } else {
        o = *(const short8*)((const u16*)src + i);
    }
    *(short8*)(dst + i) = o;
}

// ---------------------------------------------------------------------------
// cvt4: z<3 -> bf16 cvt of q/k/v; z==3 -> diff = exp(sigmoid(qde)) in f16.
// grid (n/2048, 1, 4). Fuses prep_diff into the same memory-bound launch.
// ---------------------------------------------------------------------------
__global__ __launch_bounds__(256) void cvt4(
    const void* __restrict__ s0, const void* __restrict__ s1,
    const void* __restrict__ s2, const void* __restrict__ s3,
    u16* __restrict__ d0, u16* __restrict__ d1, u16* __restrict__ d2,
    _Float16* __restrict__ d3, int n, const int* __restrict__ flag)
{
    const bool f32 = (*flag) != 0;
    const int z = blockIdx.z;
    const int i = (blockIdx.x * 256 + threadIdx.x) * 8;
    if (i >= n) return;
    if (z == 3) {
        float x[8];
        if (f32) {
            const float4* s = (const float4*)((const float*)s3 + i);
            float4 v0 = s[0], v1 = s[1];
            x[0] = v0.x; x[1] = v0.y; x[2] = v0.z; x[3] = v0.w;
            x[4] = v1.x; x[5] = v1.y; x[6] = v1.z; x[7] = v1.w;
        } else {
            short8 v8 = *(const short8*)((const u16*)s3 + i);
            #pragma unroll
            for (int j = 0; j < 8; ++j) x[j] = b2f((u16)v8[j]);
        }
        h8 o;
        #pragma unroll
        for (int j = 0; j < 8; ++j) {
            float sig = __builtin_amdgcn_rcpf(1.f + __expf(-x[j]));
            o[j] = (_Float16)__expf(sig);
        }
        *(h8*)(d3 + i) = o;
        return;
    }
    const void* src = (z == 0) ? s0 : (z == 1) ? s1 : s2;
    u16* dst = (z == 0) ? d0 : (z == 1) ? d1 : d2;
    short8 o;
    if (f32) {
        const float4* s = (const float4*)((const float*)src + i);
        float4 v0 = s[0], v1 = s[1];
        o[0] = (short)f2b(v0.x); o[1] = (short)f2b(v0.y);
        o[2] = (short)f2b(v0.z); o[3] = (short)f2b(v0.w);
        o[4] = (short)f2b(v1.x); o[5] = (short)f2b(v1.y);
        o[6] = (short)f2b(v1.z); o[7] = (short)f2b(v1.w);
    } else {
        o = *(const short8*)((const u16*)src + i);
    }
    *(short8*)(dst + i) = o;
}

// fallback separate diff kernel (used when workspace too small to fuse)
__global__ __launch_bounds__(256) void prep_diff(
    const void* __restrict__ qde, _Float16* __restrict__ diff, int n,
    const int* __restrict__ flag)
{
    const bool f32 = (*flag) != 0;
    const int i = (blockIdx.x * 256 + threadIdx.x) * 8;
    if (i >= n) return;
    float x[8];
    if (f32) {
        const float4* s = (const float4*)((const float*)qde + i);
        float4 v0 = s[0], v1 = s[1];
        x[0] = v0.x; x[1] = v0.y; x[2] = v0.z; x[3] = v0.w;
        x[4] = v1.x; x[5] = v1.y; x[6] = v1.z; x[7] = v1.w;
    } else {
        short8 v8 = *(const short8*)((const u16*)qde + i);
        #pragma unroll
        for (int j = 0; j < 8; ++j) x[j] = b2f((u16)v8[j]);
    }
    h8 o;
    #pragma unroll
    for (int j = 0; j < 8; ++j) {
        float sig = __builtin_amdgcn_rcpf(1.f + __expf(-x[j]));
        o[j] = (_Float16)__expf(sig);
    }
    *(h8*)(diff + i) = o;
}

// ---------------------------------------------------------------------------
// MFMA GEMM core (m97-style): C[m,n] = sum_k A[m,k]*W[n,k] + bias[n]
// mode 0: bf16 head-split; mode 2: f16 head-split^T (V path); mode 1: flat
// ---------------------------------------------------------------------------
#define BM 128
#define BN 128
#define BK 32

__device__ __forceinline__ void gemm_body(
    const u16* __restrict__ A, const u16* __restrict__ W,
    const void* __restrict__ bias, void* __restrict__ dst,
    bool f32, int mode, int bm, int bn, int M, int N, int K)
{
    __shared__ u16 As[BM * BK];   // 8 KB
    __shared__ u16 Bs[BN * BK];   // 8 KB
    const int t = threadIdx.x;
    const int w = t >> 6, l = t & 63, lq = l & 15, quad = l >> 4;
    const int wr = (w >> 1) * 64, wc = (w & 1) * 64;

    const int whalf = (w & 1) * 64;
    const u16* gsrc = (w < 2) ? A : W;
    const int  gbase = (w < 2) ? bm : bn;
    u16* lbase = (w < 2) ? As : Bs;

    f32x4 acc[4][4] = {};

    for (int k0 = 0; k0 < K; k0 += BK) {
        __syncthreads();
        #pragma unroll
        for (int c = 0; c < 4; ++c) {
            const int row = whalf + c * 16 + (l >> 2);
            ldsld16(gsrc + (size_t)(gbase + row) * K + k0 + (l & 3) * 8,
                    lbase + row * BK + (l & 3) * 8);
        }
        asm volatile("s_waitcnt vmcnt(0)" ::: "memory");
        __syncthreads();
        short8 af[4], bf[4];
        #pragma unroll
        for (int i = 0; i < 4; ++i)
            af[i] = *(const short8*)&As[(wr + i * 16 + lq) * BK + quad * 8];
        #pragma unroll
        for (int j = 0; j < 4; ++j)
            bf[j] = *(const short8*)&Bs[(wc + j * 16 + lq) * BK + quad * 8];
        #pragma unroll
        for (int i = 0; i < 4; ++i)
            #pragma unroll
            for (int j = 0; j < 4; ++j)
                acc[i][j] = __builtin_amdgcn_mfma_f32_16x16x32_bf16(
                    af[i], bf[j], acc[i][j], 0, 0, 0);
    }

    #pragma unroll
    for (int j = 0; j < 4; ++j) {
        const int n = bn + wc + j * 16 + lq;
        const float bb = ldf(bias, n, f32);
        #pragma unroll
        for (int i = 0; i < 4; ++i) {
            #pragma unroll
            for (int r = 0; r < 4; ++r) {
                const int m = bm + wr + i * 16 + quad * 4 + r;
                const float vout = acc[i][j][r] + bb;
                if (mode == 0) {
                    const int b = m >> 9, s = m & 511, hh = n >> 6, df = n & 63;
                    ((u16*)dst)[((((size_t)b * 8 + hh) * 512 + s) << 6) + df] = f2b(vout);
                } else if (mode == 2) {
                    const int b = m >> 9, s = m & 511, hh = n >> 6, df = n & 63;
                    _Float16 hv = (_Float16)vout;   // V stored f16 for phase-3 f16 MFMA
                    ((u16*)dst)[((((size_t)b * 8 + hh) * 64 + df) << 9) + s] = *(const u16*)&hv;
                } else {
                    stf(dst, (size_t)m * N + n, f32, vout);
                }
            }
        }
    }
}

__global__ __launch_bounds__(256) void proj3(
    const u16* __restrict__ cq, const u16* __restrict__ ck,
    const u16* __restrict__ cv, const u16* __restrict__ cWk,
    const u16* __restrict__ cWv, const void* __restrict__ bk,
    const void* __restrict__ bv, u16* __restrict__ qh, u16* __restrict__ kh,
    u16* __restrict__ vt, const int* __restrict__ flag, int M, int N, int K)
{
    const int z = blockIdx.z;
    const u16* A = (z == 0) ? cq : (z == 1) ? ck : cv;
    const u16* W = (z < 2) ? cWk : cWv;
    const void* bias = (z < 2) ? bk : bv;
    void* dst = (z == 0) ? (void*)qh : (z == 1) ? (void*)kh : (void*)vt;
    gemm_body(A, W, bias, dst, (*flag) != 0, (z < 2) ? 0 : 2,
              blockIdx.y * BM, blockIdx.x * BN, M, N, K);
}

__global__ __launch_bounds__(256) void gemm_out(
    const u16* __restrict__ A, const u16* __restrict__ W,
    const void* __restrict__ bias, void* __restrict__ dst,
    const int* __restrict__ flag, int M, int N, int K)
{
    gemm_body(A, W, bias, dst, (*flag) != 0, 1,
              blockIdx.y * BM, blockIdx.x * BN, M, N, K);
}

// ---------------------------------------------------------------------------
// Fused AKT attention. Grid 8192 (XCD-swizzled), 512 thr.
// Phase 2 is causal W-segmented AND compile-time specialized on W (template
// LW): scans fully unrolled with constant shuffle widths so bpermute
// addresses hoist out of the hot path. P + V in f16; phase 3 uses f16 MFMA.
// ---------------------------------------------------------------------------
#define QT  16
#define SRS 568   // u16 units; row = 1136 B (16B-aligned)
#define PRS 584

template<int LW>
__device__ __forceinline__ void phase2_impl(
    _Float16* __restrict__ s_h, u16* __restrict__ p_lds,
    const _Float16* __restrict__ diff, float gl2, int zp,
    int w, int l, int q0, int b)
{
    constexpr int W = 1 << LW;        // lanes per row segment
    constexpr int R = 64 >> LW;       // rows per wave-pass
    constexpr int G = 16 / R;         // wave-passes needed (2,4,8,16)
    constexpr int NP = (G + 7) / 8;   // passes per wave (1 or 2)
    const int ln = l & (W - 1);
    const int seg = l >> LW;
    const int c0 = ln * 8;
    const int cm = c0 + 8 * (c0 >> 6);

    // prefetch all passes' inputs first (static indices; hides 2nd-pass
    // global latency under 1st-pass math)
    h8 dvv[NP], svv[NP];
    #pragma unroll
    for (int pp = 0; pp < NP; ++pp) {
        const int p = pp * 8 + w;
        if (G >= 8 || p < G) {
            const int row = p * R + seg;
            const int q = q0 + row;
            dvv[pp] = *(const h8*)(diff + ((size_t)b * 512 + q) * 512 + c0);
            svv[pp] = *(const h8*)(s_h + row * SRS + cm);
        }
    }

    #pragma unroll
    for (int pp = 0; pp < NP; ++pp) {
        const int p = pp * 8 + w;
        if (G >= 8 || p < G) {
            const int row = p * R + seg;
            const int q = q0 + row;
            const h8 dv = dvv[pp];
            const h8 sv16 = svv[pp];
            float sv[8], cs[8];
            float run = 0.f;
            #pragma unroll
            for (int j = 0; j < 8; ++j) {
                float s = (c0 + j <= q) ? (float)sv16[j] : -1e30f;
                sv[j] = s;
                float pe = ex2(s);                 // softmax #1 numerator
                run += pe; cs[j] = run;
            }
            // width-W inclusive scan (fully unrolled, constant offsets)
            float incl = run;
            #pragma unroll
            for (int o = 1; o < W; o <<= 1) {
                float u = __shfl_up(incl, o, W);
                if (ln >= o) incl += u;
            }
            const float ls  = __shfl(incl, W - 1, W);   // segment total
            const float t0  = ls - incl + run;          // ls - excl_prefix
            const float grs = gl2 * rsqf(ls);           // fold 1/sqrt(ls) in
            const float qf  = (float)(q - c0);
            // decay rescore + softmax #2 (disttot == 1 identically)
            float f8v[8]; float lf = 0.f;
            #pragma unroll
            for (int j = 0; j < 8; ++j) {
                float suf  = t0 - cs[j];                // suffix sum (unnorm)
                float pos  = qf - (float)j;
                float ms   = fmaxf(suf * pos, 0.f);
                float dist = __builtin_amdgcn_sqrtf(ms);
                // gamma<0 -> arg<=0; low clamp binds: arg >= log2(1e-5)
                float a    = fmaxf(dist * grs * (float)dv[j], -16.609640474f);
                float eff  = ex2(a);
                // masked: sv=-1e30, eff>=1e-5 -> arg<=-1e25 -> f=0
                float f    = ex2(sv[j] * eff);
                f8v[j] = f; lf += f;
            }
            #pragma unroll
            for (int o = W >> 1; o > 0; o >>= 1) lf += __shfl_xor(lf, o, 64);
            float inv2 = __builtin_amdgcn_rcpf(lf);
            if (zp && q == 0) inv2 = 0.f;
            h8 pb;
            #pragma unroll
            for (int j = 0; j < 8; ++j) pb[j] = (_Float16)(f8v[j] * inv2);
            *(h8*)((_Float16*)p_lds + row * PRS + cm) = pb;
        }
    }
}

__global__ __launch_bounds__(512) void akt_attn(
    const u16* __restrict__ qh, const u16* __restrict__ kh,
    const u16* __restrict__ vt, const _Float16* __restrict__ diff,
    const void* __restrict__ gammas, const int* __restrict__ zero_pad,
    const int* __restrict__ flag, u16* __restrict__ attn)
{
    __shared__ _Float16 s_h[QT * SRS];   // 18176 B (reused as f32 partials ph3)
    __shared__ u16      p_lds[QT * PRS]; // 18688 B (f16 P)

    const int blk = blockIdx.x;
    const int h = blk & 7;               // XCD pin: (b,h) fixed per XCD
    const int i0 = blk >> 3;
    const int qt = i0 & 31;
    const int b = i0 >> 5;

    const int q0 = qt * QT;
    const int t = threadIdx.x, w = t >> 6, l = t & 63;
    const int lq = l & 15, quad = l >> 4;
    const bool f32 = (*flag) != 0;
    const size_t bh = ((size_t)b * 8 + h) * 512;
    const int qmax = q0 + QT - 1;

    // ---------------- phase 1: scores = (qh @ kh^T) * 0.125*log2e -> f16 ----
    {
        const u16* qb = qh + (bh + q0) * 64;
        short8 af0 = *(const short8*)(qb + lq * 64 +      quad * 8);
        short8 af1 = *(const short8*)(qb + lq * 64 + 32 + quad * 8);
        const u16* kb = kh + bh * 64;
        const int KT = (q0 + QT + 127) >> 7;
        int n0 = w * 16;
        bool act = (n0 <= qmax);
        short8 bf0, bf1;
        if (act) {
            bf0 = *(const short8*)(kb + (size_t)(n0 + lq) * 64 +      quad * 8);
            bf1 = *(const short8*)(kb + (size_t)(n0 + lq) * 64 + 32 + quad * 8);
        }
        for (int kt = 0; kt < KT; ++kt) {
            const int n0n = (kt + 1) * 128 + w * 16;
            const bool actn = (kt + 1 < KT) && (n0n <= qmax);
            short8 nb0, nb1;
            if (actn) {
                nb0 = *(const short8*)(kb + (size_t)(n0n + lq) * 64 +      quad * 8);
                nb1 = *(const short8*)(kb + (size_t)(n0n + lq) * 64 + 32 + quad * 8);
            }
            if (act) {
                f32x4 acc = {0.f, 0.f, 0.f, 0.f};
                acc = __builtin_amdgcn_mfma_f32_16x16x32_bf16(af0, bf0, acc, 0, 0, 0);
                acc = __builtin_amdgcn_mfma_f32_16x16x32_bf16(af1, bf1, acc, 0, 0, 0);
                const int cm = n0 + lq + 8 * (n0 >> 6);
                #pragma unroll
                for (int r = 0; r < 4; ++r)
                    s_h[(quad * 4 + r) * SRS + cm] =
                        (_Float16)(acc[r] * 0.180336880f);  // 0.125*log2e
            }
            bf0 = nb0; bf1 = nb1; act = actn; n0 = n0n;
        }
    }
    __syncthreads();

    // ---------------- phase 2: causal W-segmented rescore (specialized) -----
    {
        const float g = ldf(gammas, h, f32);
        const float gl2 = -log1pf(expf(g)) * 1.4426950408889634f; // gamma*log2e
        const int zp = zero_pad[0];
        const int need = (qmax >> 3) + 1;          // lanes of 8 cols needed
        if (need <= 8)
            phase2_impl<3>(s_h, p_lds, diff, gl2, zp, w, l, q0, b);
        else if (need <= 16)
            phase2_impl<4>(s_h, p_lds, diff, gl2, zp, w, l, q0, b);
        else if (need <= 32)
            phase2_impl<5>(s_h, p_lds, diff, gl2, zp, w, l, q0, b);
        else
            phase2_impl<6>(s_h, p_lds, diff, gl2, zp, w, l, q0, b);
    }
    __syncthreads();

    // ---------------- phase 3: O = P @ V (f16 MFMA), 8 waves (k-halves) -----
    {
        const int g = w & 3;                 // output 16-col group
        const int half = w >> 2;             // k-chunk parity
        const int KS = (qmax >> 5) + 1;
        const _Float16* vb = (const _Float16*)vt +
            ((size_t)(b * 8 + h) * 64 + g * 16 + lq) * 512;
        const _Float16* prow = (const _Float16*)p_lds + lq * PRS;
        f32x4 oacc = {0.f, 0.f, 0.f, 0.f};
        for (int ks = half; ks < KS; ks += 2) {
            const int kb2 = ks * 32 + quad * 8;
            h8 pa = *(const h8*)(prow + kb2 + 8 * (kb2 >> 6));
            h8 vv = *(const h8*)(vb + kb2);
            oacc = __builtin_amdgcn_mfma_f32_16x16x32_f16(pa, vv, oacc, 0, 0, 0);
        }
        float* opart = (float*)s_h;          // reuse score LDS (post-barrier)
        if (half == 1) {
            #pragma unroll
            for (int r = 0; r < 4; ++r)
                opart[(g * 16 + quad * 4 + r) * 17 + lq] = oacc[r];
        }
        __syncthreads();
        if (half == 0) {
            const size_t ob = ((size_t)b * 512 + q0 + quad * 4) * 512 + h * 64 + g * 16 + lq;
            #pragma unroll
            for (int r = 0; r < 4; ++r)
                attn[ob + (size_t)r * 512] =
                    f2b(oacc[r] + opart[(g * 16 + quad * 4 + r) * 17 + lq]);
        }
    }
}

// ---------------------------------------------------------------------------
extern "C" void kernel_launch(void* const* d_in, const int* in_sizes, int n_in,
                              void* d_out, int out_size, void* d_ws, size_t ws_size,
                              hipStream_t stream) {
    const void* q   = d_in[0];
    const void* k   = d_in[1];
    const void* v   = d_in[2];
    // d_in[3] = mask (tril) == (k<=q), unused
    const int*  zp  = (const int*)d_in[4];
    const void* qde = d_in[5];
    const void* Wk  = d_in[6];
    const void* bk  = d_in[7];
    const void* Wv  = d_in[8];
    const void* bv  = d_in[9];
    const void* Wo  = d_in[10];
    const void* bo  = d_in[11];
    const void* gam = d_in[12];

    const int M = 32 * 512, N = 512, K = 512;
    const int NBIG = M * K;        // 8388608
    const int NW = 512 * 512;      // 262144

    char* ws = (char*)d_ws;
    int* flag = (int*)ws;
    const size_t SZB = (size_t)NBIG * 2;   // 16.8 MB
    const size_t SZW = (size_t)NW * 2;     // 0.5 MB
    u16* cWk  = (u16*)(ws + 1024);
    u16* cWv  = (u16*)(ws + 1024 + SZW);
    u16* cWo  = (u16*)(ws + 1024 + 2 * SZW);
    u16* cq   = (u16*)(ws + 1024 + 3 * SZW);
    u16* ck   = (u16*)(ws + 1024 + 3 * SZW + SZB);
    u16* cv   = (u16*)(ws + 1024 + 3 * SZW + 2 * SZB);
    u16* qh   = (u16*)(ws + 1024 + 3 * SZW + 3 * SZB);
    u16* kh   = (u16*)(ws + 1024 + 3 * SZW + 4 * SZB);
    u16* vt   = (u16*)(ws + 1024 + 3 * SZW + 5 * SZB);   // [B,H,64,S] f16
    u16* attn = (u16*)(ws + 1024 + 3 * SZW + 6 * SZB);   // [B,S,512] bf16

    detect_f32<<<1, 256, 0, stream>>>((const u16*)q, flag);
    cvt3<<<dim3(NW / 2048, 1, 3), 256, 0, stream>>>(Wk, Wv, Wo, cWk, cWv, cWo, NW, flag);

    _Float16* diffb;
    const size_t need_ws = 1024 + 3 * SZW + 8 * SZB;   // +1 slot for fused diff
    if (ws_size >= need_ws) {
        // fused path: diff gets its own slot; one launch for q/k/v cvt + diff
        diffb = (_Float16*)(ws + 1024 + 3 * SZW + 7 * SZB);
        cvt4<<<dim3(NBIG / 2048, 1, 4), 256, 0, stream>>>(
            q, k, v, qde, cq, ck, cv, diffb, NBIG, flag);
        proj3<<<dim3(N / BN, M / BM, 3), 256, 0, stream>>>(
            cq, ck, cv, cWk, cWv, bk, bv, qh, kh, vt, flag, M, N, K);
    } else {
        // fallback: cvt then proj, then diff into dead cq slot
        cvt3<<<dim3(NBIG / 2048, 1, 3), 256, 0, stream>>>(
            q, k, v, cq, ck, cv, NBIG, flag);
        proj3<<<dim3(N / BN, M / BM, 3), 256, 0, stream>>>(
            cq, ck, cv, cWk, cWv, bk, bv, qh, kh, vt, flag, M, N, K);
        diffb = (_Float16*)cq;
        prep_diff<<<dim3(NBIG / 2048), 256, 0, stream>>>(qde, diffb, NBIG, flag);
    }

    akt_attn<<<8192, 512, 0, stream>>>(qh, kh, vt, diffb, gam, zp, flag, attn);
    gemm_out<<<dim3(N / BN, M / BM), 256, 0, stream>>>(attn, cWo, bo, d_out, flag, M, N, K);
}

// Round 6
// 381.462 us; speedup vs baseline: 1.0160x; 1.0160x over previous
//
#include <hip/hip_runtime.h>

typedef unsigned short u16;
typedef __attribute__((ext_vector_type(8))) short short8;
typedef __attribute__((ext_vector_type(8))) _Float16 h8;
typedef __attribute__((ext_vector_type(4))) float f32x4;

// ---- bf16 <-> f32 bit helpers ----
__device__ __forceinline__ float b2f(u16 u) {
    return __uint_as_float(((unsigned int)u) << 16);
}
__device__ __forceinline__ u16 f2b(float f) {
    unsigned int x = __float_as_uint(f);
    return (u16)((x + 0x7FFFu + ((x >> 16) & 1u)) >> 16);   // RNE
}
__device__ __forceinline__ float ldf(const void* p, size_t i, bool f32) {
    return f32 ? ((const float*)p)[i] : b2f(((const u16*)p)[i]);
}
__device__ __forceinline__ void stf(void* p, size_t i, bool f32, float v) {
    if (f32) ((float*)p)[i] = v; else ((u16*)p)[i] = f2b(v);
}
// raw v_exp_f32: computes 2^x in one trans op (no log2e pre-mul)
__device__ __forceinline__ float ex2(float x) {
    float r; asm("v_exp_f32 %0, %1" : "=v"(r) : "v"(x)); return r;
}
__device__ __forceinline__ float rsqf(float x) {
    float r; asm("v_rsq_f32 %0, %1" : "=v"(r) : "v"(x)); return r;
}

// ---- DPP cross-lane add helpers (VALU-speed, vs ~35cy ds_bpermute) --------
// returns dpp_mov(x) with old=0; masked/invalid lanes yield 0
template<int CTRL, int RM, bool BC>
__device__ __forceinline__ float dppmov(float x) {
    return __uint_as_float((unsigned)__builtin_amdgcn_update_dpp(
        0, (int)__float_as_uint(x), CTRL, RM, 0xF, BC));
}
// inclusive scan across W=2^LW contiguous lanes (LW in [3,6])
template<int LW>
__device__ __forceinline__ float seg_scan(float x, int ln) {
    if constexpr (LW >= 4) {
        x += dppmov<0x111, 0xF, true>(x);   // row_shr:1
        x += dppmov<0x112, 0xF, true>(x);   // row_shr:2
        x += dppmov<0x114, 0xF, true>(x);   // row_shr:4
        x += dppmov<0x118, 0xF, true>(x);   // row_shr:8  -> 16-wide
        if constexpr (LW >= 5)
            x += dppmov<0x142, 0xA, false>(x);  // row_bcast:15 -> 32-wide
        if constexpr (LW >= 6)
            x += dppmov<0x143, 0xC, false>(x);  // row_bcast:31 -> 64-wide
    } else {
        #pragma unroll
        for (int o = 1; o < (1 << LW); o <<= 1) {
            float u = __shfl_up(x, o, 1 << LW);
            if (ln >= o) x += u;
        }
    }
    return x;
}
// broadcast segment-last lane's value to the whole segment
template<int LW>
__device__ __forceinline__ float seg_bcast_last(float x) {
    if constexpr (LW == 6)
        return __uint_as_float((unsigned)__builtin_amdgcn_readlane(
            (int)__float_as_uint(x), 63));
    else
        return __shfl(x, (1 << LW) - 1, 1 << LW);
}

// async global -> LDS, 16 B per lane (dest = wave-uniform base + lane*16)
__device__ __forceinline__ void ldsld16(const void* g, void* l) {
    __builtin_amdgcn_global_load_lds(
        (const __attribute__((address_space(1))) unsigned int*)g,
        (__attribute__((address_space(3))) unsigned int*)l, 16, 0, 0);
}

// ---------------------------------------------------------------------------
// dtype probe (evidence: flag=1/f32 on this harness; keep robust)
// ---------------------------------------------------------------------------
__global__ void detect_f32(const u16* __restrict__ q, int* __restrict__ flag) {
    __shared__ int cw, cz;
    if (threadIdx.x == 0) { cw = 0; cz = 0; }
    __syncthreads();
    int w = 0, z = 0;
    for (int i = threadIdx.x; i < 4096; i += 256) {
        u16 u = q[i];
        int e = (u >> 7) & 0xFF;
        if (e >= 0xC8) w++;
        if (((i & 1) == 0) && u == 0) z++;
    }
    atomicAdd(&cw, w); atomicAdd(&cz, z);
    __syncthreads();
    if (threadIdx.x == 0) *flag = (cw > 8 || cz > 1024) ? 1 : 0;
}

// ---------------------------------------------------------------------------
// convert 3 tensors -> bf16 ws in one launch. grid (n/2048, 1, 3)
// ---------------------------------------------------------------------------
__global__ __launch_bounds__(256) void cvt3(
    const void* __restrict__ s0, const void* __restrict__ s1,
    const void* __restrict__ s2, u16* __restrict__ d0, u16* __restrict__ d1,
    u16* __restrict__ d2, int n, const int* __restrict__ flag)
{
    const bool f32 = (*flag) != 0;
    const int z = blockIdx.z;
    const void* src = (z == 0) ? s0 : (z == 1) ? s1 : s2;
    u16* dst = (z == 0) ? d0 : (z == 1) ? d1 : d2;
    const int i = (blockIdx.x * 256 + threadIdx.x) * 8;
    if (i >= n) return;
    short8 o;
    if (f32) {
        const float4* s = (const float4*)((const float*)src + i);
        float4 v0 = s[0], v1 = s[1];
        o[0] = (short)f2b(v0.x); o[1] = (short)f2b(v0.y);
        o[2] = (short)f2b(v0.z); o[3] = (short)f2b(v0.w);
        o[4] = (short)f2b(v1.x); o[5] = (short)f2b(v1.y);
        o[6] = (short)f2b(v1.z); o[7] = (short)f2b(v1.w);
    } else {
        o = *(const short8*)((const u16*)src + i);
    }
    *(short8*)(dst + i) = o;
}

// ---------------------------------------------------------------------------
// cvt4: z<3 -> bf16 cvt of q/k/v; z==3 -> diff = exp(sigmoid(qde)) in f16.
// grid (n/2048, 1, 4). Fuses prep_diff into the same memory-bound launch.
// ---------------------------------------------------------------------------
__global__ __launch_bounds__(256) void cvt4(
    const void* __restrict__ s0, const void* __restrict__ s1,
    const void* __restrict__ s2, const void* __restrict__ s3,
    u16* __restrict__ d0, u16* __restrict__ d1, u16* __restrict__ d2,
    _Float16* __restrict__ d3, int n, const int* __restrict__ flag)
{
    const bool f32 = (*flag) != 0;
    const int z = blockIdx.z;
    const int i = (blockIdx.x * 256 + threadIdx.x) * 8;
    if (i >= n) return;
    if (z == 3) {
        float x[8];
        if (f32) {
            const float4* s = (const float4*)((const float*)s3 + i);
            float4 v0 = s[0], v1 = s[1];
            x[0] = v0.x; x[1] = v0.y; x[2] = v0.z; x[3] = v0.w;
            x[4] = v1.x; x[5] = v1.y; x[6] = v1.z; x[7] = v1.w;
        } else {
            short8 v8 = *(const short8*)((const u16*)s3 + i);
            #pragma unroll
            for (int j = 0; j < 8; ++j) x[j] = b2f((u16)v8[j]);
        }
        h8 o;
        #pragma unroll
        for (int j = 0; j < 8; ++j) {
            float sig = __builtin_amdgcn_rcpf(1.f + __expf(-x[j]));
            o[j] = (_Float16)__expf(sig);
        }
        *(h8*)(d3 + i) = o;
        return;
    }
    const void* src = (z == 0) ? s0 : (z == 1) ? s1 : s2;
    u16* dst = (z == 0) ? d0 : (z == 1) ? d1 : d2;
    short8 o;
    if (f32) {
        const float4* s = (const float4*)((const float*)src + i);
        float4 v0 = s[0], v1 = s[1];
        o[0] = (short)f2b(v0.x); o[1] = (short)f2b(v0.y);
        o[2] = (short)f2b(v0.z); o[3] = (short)f2b(v0.w);
        o[4] = (short)f2b(v1.x); o[5] = (short)f2b(v1.y);
        o[6] = (short)f2b(v1.z); o[7] = (short)f2b(v1.w);
    } else {
        o = *(const short8*)((const u16*)src + i);
    }
    *(short8*)(dst + i) = o;
}

// fallback separate diff kernel (used when workspace too small to fuse)
__global__ __launch_bounds__(256) void prep_diff(
    const void* __restrict__ qde, _Float16* __restrict__ diff, int n,
    const int* __restrict__ flag)
{
    const bool f32 = (*flag) != 0;
    const int i = (blockIdx.x * 256 + threadIdx.x) * 8;
    if (i >= n) return;
    float x[8];
    if (f32) {
        const float4* s = (const float4*)((const float*)qde + i);
        float4 v0 = s[0], v1 = s[1];
        x[0] = v0.x; x[1] = v0.y; x[2] = v0.z; x[3] = v0.w;
        x[4] = v1.x; x[5] = v1.y; x[6] = v1.z; x[7] = v1.w;
    } else {
        short8 v8 = *(const short8*)((const u16*)qde + i);
        #pragma unroll
        for (int j = 0; j < 8; ++j) x[j] = b2f((u16)v8[j]);
    }
    h8 o;
    #pragma unroll
    for (int j = 0; j < 8; ++j) {
        float sig = __builtin_amdgcn_rcpf(1.f + __expf(-x[j]));
        o[j] = (_Float16)__expf(sig);
    }
    *(h8*)(diff + i) = o;
}

// ---------------------------------------------------------------------------
// MFMA GEMM core (m97-style): C[m,n] = sum_k A[m,k]*W[n,k] + bias[n]
// mode 0: bf16 head-split; mode 2: f16 head-split^T (V path); mode 1: flat
// ---------------------------------------------------------------------------
#define BM 128
#define BN 128
#define BK 32

__device__ __forceinline__ void gemm_body(
    const u16* __restrict__ A, const u16* __restrict__ W,
    const void* __restrict__ bias, void* __restrict__ dst,
    bool f32, int mode, int bm, int bn, int M, int N, int K)
{
    __shared__ u16 As[BM * BK];   // 8 KB
    __shared__ u16 Bs[BN * BK];   // 8 KB
    const int t = threadIdx.x;
    const int w = t >> 6, l = t & 63, lq = l & 15, quad = l >> 4;
    const int wr = (w >> 1) * 64, wc = (w & 1) * 64;

    const int whalf = (w & 1) * 64;
    const u16* gsrc = (w < 2) ? A : W;
    const int  gbase = (w < 2) ? bm : bn;
    u16* lbase = (w < 2) ? As : Bs;

    f32x4 acc[4][4] = {};

    for (int k0 = 0; k0 < K; k0 += BK) {
        __syncthreads();
        #pragma unroll
        for (int c = 0; c < 4; ++c) {
            const int row = whalf + c * 16 + (l >> 2);
            ldsld16(gsrc + (size_t)(gbase + row) * K + k0 + (l & 3) * 8,
                    lbase + row * BK + (l & 3) * 8);
        }
        asm volatile("s_waitcnt vmcnt(0)" ::: "memory");
        __syncthreads();
        short8 af[4], bf[4];
        #pragma unroll
        for (int i = 0; i < 4; ++i)
            af[i] = *(const short8*)&As[(wr + i * 16 + lq) * BK + quad * 8];
        #pragma unroll
        for (int j = 0; j < 4; ++j)
            bf[j] = *(const short8*)&Bs[(wc + j * 16 + lq) * BK + quad * 8];
        #pragma unroll
        for (int i = 0; i < 4; ++i)
            #pragma unroll
            for (int j = 0; j < 4; ++j)
                acc[i][j] = __builtin_amdgcn_mfma_f32_16x16x32_bf16(
                    af[i], bf[j], acc[i][j], 0, 0, 0);
    }

    #pragma unroll
    for (int j = 0; j < 4; ++j) {
        const int n = bn + wc + j * 16 + lq;
        const float bb = ldf(bias, n, f32);
        #pragma unroll
        for (int i = 0; i < 4; ++i) {
            #pragma unroll
            for (int r = 0; r < 4; ++r) {
                const int m = bm + wr + i * 16 + quad * 4 + r;
                const float vout = acc[i][j][r] + bb;
                if (mode == 0) {
                    const int b = m >> 9, s = m & 511, hh = n >> 6, df = n & 63;
                    ((u16*)dst)[((((size_t)b * 8 + hh) * 512 + s) << 6) + df] = f2b(vout);
                } else if (mode == 2) {
                    const int b = m >> 9, s = m & 511, hh = n >> 6, df = n & 63;
                    _Float16 hv = (_Float16)vout;   // V stored f16 for phase-3 f16 MFMA
                    ((u16*)dst)[((((size_t)b * 8 + hh) * 64 + df) << 9) + s] = *(const u16*)&hv;
                } else {
                    stf(dst, (size_t)m * N + n, f32, vout);
                }
            }
        }
    }
}

__global__ __launch_bounds__(256) void proj3(
    const u16* __restrict__ cq, const u16* __restrict__ ck,
    const u16* __restrict__ cv, const u16* __restrict__ cWk,
    const u16* __restrict__ cWv, const void* __restrict__ bk,
    const void* __restrict__ bv, u16* __restrict__ qh, u16* __restrict__ kh,
    u16* __restrict__ vt, const int* __restrict__ flag, int M, int N, int K)
{
    const int z = blockIdx.z;
    const u16* A = (z == 0) ? cq : (z == 1) ? ck : cv;
    const u16* W = (z < 2) ? cWk : cWv;
    const void* bias = (z < 2) ? bk : bv;
    void* dst = (z == 0) ? (void*)qh : (z == 1) ? (void*)kh : (void*)vt;
    gemm_body(A, W, bias, dst, (*flag) != 0, (z < 2) ? 0 : 2,
              blockIdx.y * BM, blockIdx.x * BN, M, N, K);
}

__global__ __launch_bounds__(256) void gemm_out(
    const u16* __restrict__ A, const u16* __restrict__ W,
    const void* __restrict__ bias, void* __restrict__ dst,
    const int* __restrict__ flag, int M, int N, int K)
{
    gemm_body(A, W, bias, dst, (*flag) != 0, 1,
              blockIdx.y * BM, blockIdx.x * BN, M, N, K);
}

// ---------------------------------------------------------------------------
// Fused AKT attention. Grid 8192, 512 thr. LPT order: heavy qt first.
// Phase 2: causal W-segmented, compile-time specialized on W, with DPP-based
// scans/reduces (VALU latency) instead of bpermute shuffles (LDS latency).
// P + V in f16; phase 3 uses f16 MFMA.
// ---------------------------------------------------------------------------
#define QT  16
#define SRS 568   // u16 units; row = 1136 B (16B-aligned)
#define PRS 584

template<int LW>
__device__ __forceinline__ void phase2_impl(
    _Float16* __restrict__ s_h, u16* __restrict__ p_lds,
    const _Float16* __restrict__ diff, float gl2, int zp,
    int w, int l, int q0, int b)
{
    constexpr int W = 1 << LW;        // lanes per row segment
    constexpr int R = 64 >> LW;       // rows per wave-pass
    constexpr int G = 16 / R;         // wave-passes needed (2,4,8,16)
    constexpr int NP = (G + 7) / 8;   // passes per wave (1 or 2)
    const int ln = l & (W - 1);
    const int seg = l >> LW;
    const int c0 = ln * 8;
    const int cm = c0 + 8 * (c0 >> 6);

    // prefetch all passes' inputs first (static indices; hides 2nd-pass
    // global latency under 1st-pass math)
    h8 dvv[NP], svv[NP];
    #pragma unroll
    for (int pp = 0; pp < NP; ++pp) {
        const int p = pp * 8 + w;
        if (G >= 8 || p < G) {
            const int row = p * R + seg;
            const int q = q0 + row;
            dvv[pp] = *(const h8*)(diff + ((size_t)b * 512 + q) * 512 + c0);
            svv[pp] = *(const h8*)(s_h + row * SRS + cm);
        }
    }

    #pragma unroll
    for (int pp = 0; pp < NP; ++pp) {
        const int p = pp * 8 + w;
        if (G >= 8 || p < G) {
            const int row = p * R + seg;
            const int q = q0 + row;
            const h8 dv = dvv[pp];
            const h8 sv16 = svv[pp];
            float sv[8], cs[8];
            float run = 0.f;
            #pragma unroll
            for (int j = 0; j < 8; ++j) {
                float s = (c0 + j <= q) ? (float)sv16[j] : -1e30f;
                sv[j] = s;
                float pe = ex2(s);                 // softmax #1 numerator
                run += pe; cs[j] = run;
            }
            // width-W inclusive scan: DPP adds (VALU) instead of bpermute
            const float incl = seg_scan<LW>(run, ln);
            const float ls   = seg_bcast_last<LW>(incl);   // segment total
            const float t0   = ls - incl + run;            // ls - excl_prefix
            const float grs  = gl2 * rsqf(ls);             // fold 1/sqrt(ls)
            const float qf   = (float)(q - c0);
            // decay rescore + softmax #2 (disttot == 1 identically)
            float f8v[8]; float lf = 0.f;
            #pragma unroll
            for (int j = 0; j < 8; ++j) {
                float suf  = t0 - cs[j];                // suffix sum (unnorm)
                float pos  = qf - (float)j;
                float ms   = fmaxf(suf * pos, 0.f);
                float dist = __builtin_amdgcn_sqrtf(ms);
                // gamma<0 -> arg<=0; low clamp binds: arg >= log2(1e-5)
                float a    = fmaxf(dist * grs * (float)dv[j], -16.609640474f);
                float eff  = ex2(a);
                // masked: sv=-1e30, eff>=1e-5 -> arg<=-1e25 -> f=0
                float f    = ex2(sv[j] * eff);
                f8v[j] = f; lf += f;
            }
            // segment-sum of lf: DPP scan + one broadcast (was log2(W) bperm)
            if constexpr (LW == 3) {
                lf += __shfl_xor(lf, 4, 64);
                lf += __shfl_xor(lf, 2, 64);
                lf += __shfl_xor(lf, 1, 64);
            } else {
                lf = seg_bcast_last<LW>(seg_scan<LW>(lf, ln));
            }
            float inv2 = __builtin_amdgcn_rcpf(lf);
            if (zp && q == 0) inv2 = 0.f;
            h8 pb;
            #pragma unroll
            for (int j = 0; j < 8; ++j) pb[j] = (_Float16)(f8v[j] * inv2);
            *(h8*)((_Float16*)p_lds + row * PRS + cm) = pb;
        }
    }
}

__global__ __launch_bounds__(512) void akt_attn(
    const u16* __restrict__ qh, const u16* __restrict__ kh,
    const u16* __restrict__ vt, const _Float16* __restrict__ diff,
    const void* __restrict__ gammas, const int* __restrict__ zero_pad,
    const int* __restrict__ flag, u16* __restrict__ attn)
{
    __shared__ _Float16 s_h[QT * SRS];   // 18176 B (reused as f32 partials ph3)
    __shared__ u16      p_lds[QT * PRS]; // 18688 B (f16 P)

    const int blk = blockIdx.x;
    const int h = blk & 7;               // XCD pin: (b,h) fixed per XCD
    const int i0 = blk >> 3;
    const int qt = 31 - (i0 & 31);       // LPT: heaviest Q-tiles dispatch first
    const int b = i0 >> 5;

    const int q0 = qt * QT;
    const int t = threadIdx.x, w = t >> 6, l = t & 63;
    const int lq = l & 15, quad = l >> 4;
    const bool f32 = (*flag) != 0;
    const size_t bh = ((size_t)b * 8 + h) * 512;
    const int qmax = q0 + QT - 1;

    // ---------------- phase 1: scores = (qh @ kh^T) * 0.125*log2e -> f16 ----
    {
        const u16* qb = qh + (bh + q0) * 64;
        short8 af0 = *(const short8*)(qb + lq * 64 +      quad * 8);
        short8 af1 = *(const short8*)(qb + lq * 64 + 32 + quad * 8);
        const u16* kb = kh + bh * 64;
        const int KT = (q0 + QT + 127) >> 7;
        int n0 = w * 16;
        bool act = (n0 <= qmax);
        short8 bf0, bf1;
        if (act) {
            bf0 = *(const short8*)(kb + (size_t)(n0 + lq) * 64 +      quad * 8);
            bf1 = *(const short8*)(kb + (size_t)(n0 + lq) * 64 + 32 + quad * 8);
        }
        for (int kt = 0; kt < KT; ++kt) {
            const int n0n = (kt + 1) * 128 + w * 16;
            const bool actn = (kt + 1 < KT) && (n0n <= qmax);
            short8 nb0, nb1;
            if (actn) {
                nb0 = *(const short8*)(kb + (size_t)(n0n + lq) * 64 +      quad * 8);
                nb1 = *(const short8*)(kb + (size_t)(n0n + lq) * 64 + 32 + quad * 8);
            }
            if (act) {
                f32x4 acc = {0.f, 0.f, 0.f, 0.f};
                acc = __builtin_amdgcn_mfma_f32_16x16x32_bf16(af0, bf0, acc, 0, 0, 0);
                acc = __builtin_amdgcn_mfma_f32_16x16x32_bf16(af1, bf1, acc, 0, 0, 0);
                const int cm = n0 + lq + 8 * (n0 >> 6);
                #pragma unroll
                for (int r = 0; r < 4; ++r)
                    s_h[(quad * 4 + r) * SRS + cm] =
                        (_Float16)(acc[r] * 0.180336880f);  // 0.125*log2e
            }
            bf0 = nb0; bf1 = nb1; act = actn; n0 = n0n;
        }
    }
    __syncthreads();

    // ---------------- phase 2: causal W-segmented rescore (specialized) -----
    {
        const float g = ldf(gammas, h, f32);
        const float gl2 = -log1pf(expf(g)) * 1.4426950408889634f; // gamma*log2e
        const int zp = zero_pad[0];
        const int need = (qmax >> 3) + 1;          // lanes of 8 cols needed
        if (need <= 8)
            phase2_impl<3>(s_h, p_lds, diff, gl2, zp, w, l, q0, b);
        else if (need <= 16)
            phase2_impl<4>(s_h, p_lds, diff, gl2, zp, w, l, q0, b);
        else if (need <= 32)
            phase2_impl<5>(s_h, p_lds, diff, gl2, zp, w, l, q0, b);
        else
            phase2_impl<6>(s_h, p_lds, diff, gl2, zp, w, l, q0, b);
    }
    __syncthreads();

    // ---------------- phase 3: O = P @ V (f16 MFMA), 8 waves (k-halves) -----
    {
        const int g = w & 3;                 // output 16-col group
        const int half = w >> 2;             // k-chunk parity
        const int KS = (qmax >> 5) + 1;
        const _Float16* vb = (const _Float16*)vt +
            ((size_t)(b * 8 + h) * 64 + g * 16 + lq) * 512;
        const _Float16* prow = (const _Float16*)p_lds + lq * PRS;
        f32x4 oacc = {0.f, 0.f, 0.f, 0.f};
        for (int ks = half; ks < KS; ks += 2) {
            const int kb2 = ks * 32 + quad * 8;
            h8 pa = *(const h8*)(prow + kb2 + 8 * (kb2 >> 6));
            h8 vv = *(const h8*)(vb + kb2);
            oacc = __builtin_amdgcn_mfma_f32_16x16x32_f16(pa, vv, oacc, 0, 0, 0);
        }
        float* opart = (float*)s_h;          // reuse score LDS (post-barrier)
        if (half == 1) {
            #pragma unroll
            for (int r = 0; r < 4; ++r)
                opart[(g * 16 + quad * 4 + r) * 17 + lq] = oacc[r];
        }
        __syncthreads();
        if (half == 0) {
            const size_t ob = ((size_t)b * 512 + q0 + quad * 4) * 512 + h * 64 + g * 16 + lq;
            #pragma unroll
            for (int r = 0; r < 4; ++r)
                attn[ob + (size_t)r * 512] =
                    f2b(oacc[r] + opart[(g * 16 + quad * 4 + r) * 17 + lq]);
        }
    }
}

// ---------------------------------------------------------------------------
extern "C" void kernel_launch(void* const* d_in, const int* in_sizes, int n_in,
                              void* d_out, int out_size, void* d_ws, size_t ws_size,
                              hipStream_t stream) {
    const void* q   = d_in[0];
    const void* k   = d_in[1];
    const void* v   = d_in[2];
    // d_in[3] = mask (tril) == (k<=q), unused
    const int*  zp  = (const int*)d_in[4];
    const void* qde = d_in[5];
    const void* Wk  = d_in[6];
    const void* bk  = d_in[7];
    const void* Wv  = d_in[8];
    const void* bv  = d_in[9];
    const void* Wo  = d_in[10];
    const void* bo  = d_in[11];
    const void* gam = d_in[12];

    const int M = 32 * 512, N = 512, K = 512;
    const int NBIG = M * K;        // 8388608
    const int NW = 512 * 512;      // 262144

    char* ws = (char*)d_ws;
    int* flag = (int*)ws;
    const size_t SZB = (size_t)NBIG * 2;   // 16.8 MB
    const size_t SZW = (size_t)NW * 2;     // 0.5 MB
    u16* cWk  = (u16*)(ws + 1024);
    u16* cWv  = (u16*)(ws + 1024 + SZW);
    u16* cWo  = (u16*)(ws + 1024 + 2 * SZW);
    u16* cq   = (u16*)(ws + 1024 + 3 * SZW);
    u16* ck   = (u16*)(ws + 1024 + 3 * SZW + SZB);
    u16* cv   = (u16*)(ws + 1024 + 3 * SZW + 2 * SZB);
    u16* qh   = (u16*)(ws + 1024 + 3 * SZW + 3 * SZB);
    u16* kh   = (u16*)(ws + 1024 + 3 * SZW + 4 * SZB);
    u16* vt   = (u16*)(ws + 1024 + 3 * SZW + 5 * SZB);   // [B,H,64,S] f16
    u16* attn = (u16*)(ws + 1024 + 3 * SZW + 6 * SZB);   // [B,S,512] bf16

    detect_f32<<<1, 256, 0, stream>>>((const u16*)q, flag);
    cvt3<<<dim3(NW / 2048, 1, 3), 256, 0, stream>>>(Wk, Wv, Wo, cWk, cWv, cWo, NW, flag);

    _Float16* diffb;
    const size_t need_ws = 1024 + 3 * SZW + 8 * SZB;   // +1 slot for fused diff
    if (ws_size >= need_ws) {
        // fused path: diff gets its own slot; one launch for q/k/v cvt + diff
        diffb = (_Float16*)(ws + 1024 + 3 * SZW + 7 * SZB);
        cvt4<<<dim3(NBIG / 2048, 1, 4), 256, 0, stream>>>(
            q, k, v, qde, cq, ck, cv, diffb, NBIG, flag);
        proj3<<<dim3(N / BN, M / BM, 3), 256, 0, stream>>>(
            cq, ck, cv, cWk, cWv, bk, bv, qh, kh, vt, flag, M, N, K);
    } else {
        // fallback: cvt then proj, then diff into dead cq slot
        cvt3<<<dim3(NBIG / 2048, 1, 3), 256, 0, stream>>>(
            q, k, v, cq, ck, cv, NBIG, flag);
        proj3<<<dim3(N / BN, M / BM, 3), 256, 0, stream>>>(
            cq, ck, cv, cWk, cWv, bk, bv, qh, kh, vt, flag, M, N, K);
        diffb = (_Float16*)cq;
        prep_diff<<<dim3(NBIG / 2048), 256, 0, stream>>>(qde, diffb, NBIG, flag);
    }

    akt_attn<<<8192, 512, 0, stream>>>(qh, kh, vt, diffb, gam, zp, flag, attn);
    gemm_out<<<dim3(N / BN, M / BM), 256, 0, stream>>>(attn, cWo, bo, d_out, flag, M, N, K);
}

// Round 7
// 370.621 us; speedup vs baseline: 1.0457x; 1.0293x over previous
//
#include <hip/hip_runtime.h>

typedef unsigned short u16;
typedef __attribute__((ext_vector_type(8))) short short8;
typedef __attribute__((ext_vector_type(8))) _Float16 h8;
typedef __attribute__((ext_vector_type(4))) float f32x4;

// ---- bf16 <-> f32 bit helpers ----
__device__ __forceinline__ float b2f(u16 u) {
    return __uint_as_float(((unsigned int)u) << 16);
}
__device__ __forceinline__ u16 f2b(float f) {
    unsigned int x = __float_as_uint(f);
    return (u16)((x + 0x7FFFu + ((x >> 16) & 1u)) >> 16);   // RNE
}
__device__ __forceinline__ float ldf(const void* p, size_t i, bool f32) {
    return f32 ? ((const float*)p)[i] : b2f(((const u16*)p)[i]);
}
__device__ __forceinline__ void stf(void* p, size_t i, bool f32, float v) {
    if (f32) ((float*)p)[i] = v; else ((u16*)p)[i] = f2b(v);
}
// raw v_exp_f32: computes 2^x in one trans op (no log2e pre-mul)
__device__ __forceinline__ float ex2(float x) {
    float r; asm("v_exp_f32 %0, %1" : "=v"(r) : "v"(x)); return r;
}
__device__ __forceinline__ float rsqf(float x) {
    float r; asm("v_rsq_f32 %0, %1" : "=v"(r) : "v"(x)); return r;
}

// ---- DPP cross-lane add helpers (VALU-speed, vs ~35cy ds_bpermute) --------
template<int CTRL, int RM, bool BC>
__device__ __forceinline__ float dppmov(float x) {
    return __uint_as_float((unsigned)__builtin_amdgcn_update_dpp(
        0, (int)__float_as_uint(x), CTRL, RM, 0xF, BC));
}
// inclusive scan across W=2^LW contiguous lanes (LW in [3,6])
template<int LW>
__device__ __forceinline__ float seg_scan(float x, int ln) {
    if constexpr (LW >= 4) {
        x += dppmov<0x111, 0xF, true>(x);   // row_shr:1
        x += dppmov<0x112, 0xF, true>(x);   // row_shr:2
        x += dppmov<0x114, 0xF, true>(x);   // row_shr:4
        x += dppmov<0x118, 0xF, true>(x);   // row_shr:8  -> 16-wide
        if constexpr (LW >= 5)
            x += dppmov<0x142, 0xA, false>(x);  // row_bcast:15 -> 32-wide
        if constexpr (LW >= 6)
            x += dppmov<0x143, 0xC, false>(x);  // row_bcast:31 -> 64-wide
    } else {
        #pragma unroll
        for (int o = 1; o < (1 << LW); o <<= 1) {
            float u = __shfl_up(x, o, 1 << LW);
            if (ln >= o) x += u;
        }
    }
    return x;
}
// broadcast segment-last lane's value to the whole segment
template<int LW>
__device__ __forceinline__ float seg_bcast_last(float x) {
    if constexpr (LW == 6)
        return __uint_as_float((unsigned)__builtin_amdgcn_readlane(
            (int)__float_as_uint(x), 63));
    else
        return __shfl(x, (1 << LW) - 1, 1 << LW);
}

// async global -> LDS, 16 B per lane (dest = wave-uniform base + lane*16)
__device__ __forceinline__ void ldsld16(const void* g, void* l) {
    __builtin_amdgcn_global_load_lds(
        (const __attribute__((address_space(1))) unsigned int*)g,
        (__attribute__((address_space(3))) unsigned int*)l, 16, 0, 0);
}

// ---------------------------------------------------------------------------
// dtype probe (evidence: flag=1/f32 on this harness; keep robust)
// ---------------------------------------------------------------------------
__global__ void detect_f32(const u16* __restrict__ q, int* __restrict__ flag) {
    __shared__ int cw, cz;
    if (threadIdx.x == 0) { cw = 0; cz = 0; }
    __syncthreads();
    int w = 0, z = 0;
    for (int i = threadIdx.x; i < 4096; i += 256) {
        u16 u = q[i];
        int e = (u >> 7) & 0xFF;
        if (e >= 0xC8) w++;
        if (((i & 1) == 0) && u == 0) z++;
    }
    atomicAdd(&cw, w); atomicAdd(&cz, z);
    __syncthreads();
    if (threadIdx.x == 0) *flag = (cw > 8 || cz > 1024) ? 1 : 0;
}

// ---------------------------------------------------------------------------
// convert 3 tensors -> bf16 ws in one launch. grid (n/2048, 1, 3)
// ---------------------------------------------------------------------------
__global__ __launch_bounds__(256) void cvt3(
    const void* __restrict__ s0, const void* __restrict__ s1,
    const void* __restrict__ s2, u16* __restrict__ d0, u16* __restrict__ d1,
    u16* __restrict__ d2, int n, const int* __restrict__ flag)
{
    const bool f32 = (*flag) != 0;
    const int z = blockIdx.z;
    const void* src = (z == 0) ? s0 : (z == 1) ? s1 : s2;
    u16* dst = (z == 0) ? d0 : (z == 1) ? d1 : d2;
    const int i = (blockIdx.x * 256 + threadIdx.x) * 8;
    if (i >= n) return;
    short8 o;
    if (f32) {
        const float4* s = (const float4*)((const float*)src + i);
        float4 v0 = s[0], v1 = s[1];
        o[0] = (short)f2b(v0.x); o[1] = (short)f2b(v0.y);
        o[2] = (short)f2b(v0.z); o[3] = (short)f2b(v0.w);
        o[4] = (short)f2b(v1.x); o[5] = (short)f2b(v1.y);
        o[6] = (short)f2b(v1.z); o[7] = (short)f2b(v1.w);
    } else {
        o = *(const short8*)((const u16*)src + i);
    }
    *(short8*)(dst + i) = o;
}

// ---------------------------------------------------------------------------
// cvt4: z<3 -> bf16 cvt of q/k/v; z==3 -> diff = exp(sigmoid(qde)) in f16.
// grid (n/2048, 1, 4). Fuses prep_diff into the same memory-bound launch.
// ---------------------------------------------------------------------------
__global__ __launch_bounds__(256) void cvt4(
    const void* __restrict__ s0, const void* __restrict__ s1,
    const void* __restrict__ s2, const void* __restrict__ s3,
    u16* __restrict__ d0, u16* __restrict__ d1, u16* __restrict__ d2,
    _Float16* __restrict__ d3, int n, const int* __restrict__ flag)
{
    const bool f32 = (*flag) != 0;
    const int z = blockIdx.z;
    const int i = (blockIdx.x * 256 + threadIdx.x) * 8;
    if (i >= n) return;
    if (z == 3) {
        float x[8];
        if (f32) {
            const float4* s = (const float4*)((const float*)s3 + i);
            float4 v0 = s[0], v1 = s[1];
            x[0] = v0.x; x[1] = v0.y; x[2] = v0.z; x[3] = v0.w;
            x[4] = v1.x; x[5] = v1.y; x[6] = v1.z; x[7] = v1.w;
        } else {
            short8 v8 = *(const short8*)((const u16*)s3 + i);
            #pragma unroll
            for (int j = 0; j < 8; ++j) x[j] = b2f((u16)v8[j]);
        }
        h8 o;
        #pragma unroll
        for (int j = 0; j < 8; ++j) {
            float sig = __builtin_amdgcn_rcpf(1.f + __expf(-x[j]));
            o[j] = (_Float16)__expf(sig);
        }
        *(h8*)(d3 + i) = o;
        return;
    }
    const void* src = (z == 0) ? s0 : (z == 1) ? s1 : s2;
    u16* dst = (z == 0) ? d0 : (z == 1) ? d1 : d2;
    short8 o;
    if (f32) {
        const float4* s = (const float4*)((const float*)src + i);
        float4 v0 = s[0], v1 = s[1];
        o[0] = (short)f2b(v0.x); o[1] = (short)f2b(v0.y);
        o[2] = (short)f2b(v0.z); o[3] = (short)f2b(v0.w);
        o[4] = (short)f2b(v1.x); o[5] = (short)f2b(v1.y);
        o[6] = (short)f2b(v1.z); o[7] = (short)f2b(v1.w);
    } else {
        o = *(const short8*)((const u16*)src + i);
    }
    *(short8*)(dst + i) = o;
}

// fallback separate diff kernel (used when workspace too small to fuse)
__global__ __launch_bounds__(256) void prep_diff(
    const void* __restrict__ qde, _Float16* __restrict__ diff, int n,
    const int* __restrict__ flag)
{
    const bool f32 = (*flag) != 0;
    const int i = (blockIdx.x * 256 + threadIdx.x) * 8;
    if (i >= n) return;
    float x[8];
    if (f32) {
        const float4* s = (const float4*)((const float*)qde + i);
        float4 v0 = s[0], v1 = s[1];
        x[0] = v0.x; x[1] = v0.y; x[2] = v0.z; x[3] = v0.w;
        x[4] = v1.x; x[5] = v1.y; x[6] = v1.z; x[7] = v1.w;
    } else {
        short8 v8 = *(const short8*)((const u16*)qde + i);
        #pragma unroll
        for (int j = 0; j < 8; ++j) x[j] = b2f((u16)v8[j]);
    }
    h8 o;
    #pragma unroll
    for (int j = 0; j < 8; ++j) {
        float sig = __builtin_amdgcn_rcpf(1.f + __expf(-x[j]));
        o[j] = (_Float16)__expf(sig);
    }
    *(h8*)(diff + i) = o;
}

// ---------------------------------------------------------------------------
// MFMA GEMM core (m97-style): C[m,n] = sum_k A[m,k]*W[n,k] + bias[n]
// mode 0: bf16 head-split; mode 2: f16 head-split^T (V path); mode 1: flat
// ---------------------------------------------------------------------------
#define BM 128
#define BN 128
#define BK 32

__device__ __forceinline__ void gemm_body(
    const u16* __restrict__ A, const u16* __restrict__ W,
    const void* __restrict__ bias, void* __restrict__ dst,
    bool f32, int mode, int bm, int bn, int M, int N, int K)
{
    __shared__ u16 As[BM * BK];   // 8 KB
    __shared__ u16 Bs[BN * BK];   // 8 KB
    const int t = threadIdx.x;
    const int w = t >> 6, l = t & 63, lq = l & 15, quad = l >> 4;
    const int wr = (w >> 1) * 64, wc = (w & 1) * 64;

    const int whalf = (w & 1) * 64;
    const u16* gsrc = (w < 2) ? A : W;
    const int  gbase = (w < 2) ? bm : bn;
    u16* lbase = (w < 2) ? As : Bs;

    f32x4 acc[4][4] = {};

    for (int k0 = 0; k0 < K; k0 += BK) {
        __syncthreads();
        #pragma unroll
        for (int c = 0; c < 4; ++c) {
            const int row = whalf + c * 16 + (l >> 2);
            ldsld16(gsrc + (size_t)(gbase + row) * K + k0 + (l & 3) * 8,
                    lbase + row * BK + (l & 3) * 8);
        }
        asm volatile("s_waitcnt vmcnt(0)" ::: "memory");
        __syncthreads();
        short8 af[4], bf[4];
        #pragma unroll
        for (int i = 0; i < 4; ++i)
            af[i] = *(const short8*)&As[(wr + i * 16 + lq) * BK + quad * 8];
        #pragma unroll
        for (int j = 0; j < 4; ++j)
            bf[j] = *(const short8*)&Bs[(wc + j * 16 + lq) * BK + quad * 8];
        #pragma unroll
        for (int i = 0; i < 4; ++i)
            #pragma unroll
            for (int j = 0; j < 4; ++j)
                acc[i][j] = __builtin_amdgcn_mfma_f32_16x16x32_bf16(
                    af[i], bf[j], acc[i][j], 0, 0, 0);
    }

    #pragma unroll
    for (int j = 0; j < 4; ++j) {
        const int n = bn + wc + j * 16 + lq;
        const float bb = ldf(bias, n, f32);
        #pragma unroll
        for (int i = 0; i < 4; ++i) {
            #pragma unroll
            for (int r = 0; r < 4; ++r) {
                const int m = bm + wr + i * 16 + quad * 4 + r;
                const float vout = acc[i][j][r] + bb;
                if (mode == 0) {
                    const int b = m >> 9, s = m & 511, hh = n >> 6, df = n & 63;
                    ((u16*)dst)[((((size_t)b * 8 + hh) * 512 + s) << 6) + df] = f2b(vout);
                } else if (mode == 2) {
                    const int b = m >> 9, s = m & 511, hh = n >> 6, df = n & 63;
                    _Float16 hv = (_Float16)vout;   // V stored f16 for phase-3 f16 MFMA
                    ((u16*)dst)[((((size_t)b * 8 + hh) * 64 + df) << 9) + s] = *(const u16*)&hv;
                } else {
                    stf(dst, (size_t)m * N + n, f32, vout);
                }
            }
        }
    }
}

__global__ __launch_bounds__(256) void proj3(
    const u16* __restrict__ cq, const u16* __restrict__ ck,
    const u16* __restrict__ cv, const u16* __restrict__ cWk,
    const u16* __restrict__ cWv, const void* __restrict__ bk,
    const void* __restrict__ bv, u16* __restrict__ qh, u16* __restrict__ kh,
    u16* __restrict__ vt, const int* __restrict__ flag, int M, int N, int K)
{
    const int z = blockIdx.z;
    const u16* A = (z == 0) ? cq : (z == 1) ? ck : cv;
    const u16* W = (z < 2) ? cWk : cWv;
    const void* bias = (z < 2) ? bk : bv;
    void* dst = (z == 0) ? (void*)qh : (z == 1) ? (void*)kh : (void*)vt;
    gemm_body(A, W, bias, dst, (*flag) != 0, (z < 2) ? 0 : 2,
              blockIdx.y * BM, blockIdx.x * BN, M, N, K);
}

__global__ __launch_bounds__(256) void gemm_out(
    const u16* __restrict__ A, const u16* __restrict__ W,
    const void* __restrict__ bias, void* __restrict__ dst,
    const int* __restrict__ flag, int M, int N, int K)
{
    gemm_body(A, W, bias, dst, (*flag) != 0, 1,
              blockIdx.y * BM, blockIdx.x * BN, M, N, K);
}

// ---------------------------------------------------------------------------
// Fused AKT attention. Grid 8192, 256 thr (4 waves), 8 blocks/CU.
// Single LDS buffer: phase 1 writes scores; phase 2 rescHores IN PLACE
// (rows are wave-exclusive, read-before-write per row); phase 3 reads P,
// each wave owns one 16-col output group over full K (no partial reduce).
// 2 barriers/block, 8 independent barrier domains per CU for phase mixing.
// ---------------------------------------------------------------------------
#define QT  16
#define SRS 568   // f16 units; row = 1136 B (16B-aligned)

template<int LW>
__device__ __forceinline__ void phase2_impl(
    _Float16* __restrict__ s_h, const _Float16* __restrict__ diff,
    float gl2, int zp, int w, int l, int q0, int b)
{
    constexpr int W = 1 << LW;        // lanes per row segment
    constexpr int R = 64 >> LW;       // rows per wave-pass
    constexpr int G = 16 / R;         // wave-passes needed (2,4,8,16)
    constexpr int NP = (G + 3) / 4;   // passes per wave (1,1,2,4)
    const int ln = l & (W - 1);
    const int seg = l >> LW;
    const int c0 = ln * 8;
    const int cm = c0 + 8 * (c0 >> 6);

    #pragma unroll
    for (int pp = 0; pp < NP; ++pp) {
        const int p = pp * 4 + w;
        if (G >= 4 || p < G) {
            const int row = p * R + seg;
            const int q = q0 + row;
            const h8 dv = *(const h8*)(diff + ((size_t)b * 512 + q) * 512 + c0);
            const h8 sv16 = *(const h8*)(s_h + row * SRS + cm);
            float sv[8], cs[8];
            float run = 0.f;
            #pragma unroll
            for (int j = 0; j < 8; ++j) {
                float s = (c0 + j <= q) ? (float)sv16[j] : -1e30f;
                sv[j] = s;
                float pe = ex2(s);                 // softmax #1 numerator
                run += pe; cs[j] = run;
            }
            // width-W inclusive scan: DPP adds (VALU) instead of bpermute
            const float incl = seg_scan<LW>(run, ln);
            const float ls   = seg_bcast_last<LW>(incl);   // segment total
            const float t0   = ls - incl + run;            // ls - excl_prefix
            const float grs  = gl2 * rsqf(ls);             // fold 1/sqrt(ls)
            const float qf   = (float)(q - c0);
            // decay rescore + softmax #2 (disttot == 1 identically)
            float f8v[8]; float lf = 0.f;
            #pragma unroll
            for (int j = 0; j < 8; ++j) {
                float suf  = t0 - cs[j];                // suffix sum (unnorm)
                float pos  = qf - (float)j;
                float ms   = fmaxf(suf * pos, 0.f);
                float dist = __builtin_amdgcn_sqrtf(ms);
                // gamma<0 -> arg<=0; low clamp binds: arg >= log2(1e-5)
                float a    = fmaxf(dist * grs * (float)dv[j], -16.609640474f);
                float eff  = ex2(a);
                // masked: sv=-1e30, eff>=1e-5 -> arg<=-1e25 -> f=0
                float f    = ex2(sv[j] * eff);
                f8v[j] = f; lf += f;
            }
            // segment-sum of lf: DPP scan + one broadcast
            if constexpr (LW == 3) {
                lf += __shfl_xor(lf, 4, 64);
                lf += __shfl_xor(lf, 2, 64);
                lf += __shfl_xor(lf, 1, 64);
            } else {
                lf = seg_bcast_last<LW>(seg_scan<LW>(lf, ln));
            }
            float inv2 = __builtin_amdgcn_rcpf(lf);
            if (zp && q == 0) inv2 = 0.f;
            h8 pb;
            #pragma unroll
            for (int j = 0; j < 8; ++j) pb[j] = (_Float16)(f8v[j] * inv2);
            *(h8*)(s_h + row * SRS + cm) = pb;     // in-place: scores -> P
        }
    }
}

__global__ __launch_bounds__(256, 8) void akt_attn(
    const u16* __restrict__ qh, const u16* __restrict__ kh,
    const u16* __restrict__ vt, const _Float16* __restrict__ diff,
    const void* __restrict__ gammas, const int* __restrict__ zero_pad,
    const int* __restrict__ flag, u16* __restrict__ attn)
{
    __shared__ _Float16 s_h[QT * SRS];   // 18176 B (scores, then P in place)

    const int blk = blockIdx.x;
    const int h = blk & 7;               // XCD pin: (b,h) fixed per XCD
    const int i0 = blk >> 3;
    const int qt = 31 - (i0 & 31);       // LPT: heaviest Q-tiles dispatch first
    const int b = i0 >> 5;

    const int q0 = qt * QT;
    const int t = threadIdx.x, w = t >> 6, l = t & 63;
    const int lq = l & 15, quad = l >> 4;
    const bool f32 = (*flag) != 0;
    const size_t bh = ((size_t)b * 8 + h) * 512;
    const int qmax = q0 + QT - 1;

    // ---------------- phase 1: scores = (qh @ kh^T) * 0.125*log2e -> f16 ----
    // 4 waves x 16 cols = 64-col sweeps
    {
        const u16* qb = qh + (bh + q0) * 64;
        short8 af0 = *(const short8*)(qb + lq * 64 +      quad * 8);
        short8 af1 = *(const short8*)(qb + lq * 64 + 32 + quad * 8);
        const u16* kb = kh + bh * 64;
        const int KT = (q0 + QT + 63) >> 6;
        int n0 = w * 16;
        bool act = (n0 <= qmax);
        short8 bf0, bf1;
        if (act) {
            bf0 = *(const short8*)(kb + (size_t)(n0 + lq) * 64 +      quad * 8);
            bf1 = *(const short8*)(kb + (size_t)(n0 + lq) * 64 + 32 + quad * 8);
        }
        for (int kt = 0; kt < KT; ++kt) {
            const int n0n = (kt + 1) * 64 + w * 16;
            const bool actn = (kt + 1 < KT) && (n0n <= qmax);
            short8 nb0, nb1;
            if (actn) {
                nb0 = *(const short8*)(kb + (size_t)(n0n + lq) * 64 +      quad * 8);
                nb1 = *(const short8*)(kb + (size_t)(n0n + lq) * 64 + 32 + quad * 8);
            }
            if (act) {
                f32x4 acc = {0.f, 0.f, 0.f, 0.f};
                acc = __builtin_amdgcn_mfma_f32_16x16x32_bf16(af0, bf0, acc, 0, 0, 0);
                acc = __builtin_amdgcn_mfma_f32_16x16x32_bf16(af1, bf1, acc, 0, 0, 0);
                const int cm = n0 + lq + 8 * (n0 >> 6);
                #pragma unroll
                for (int r = 0; r < 4; ++r)
                    s_h[(quad * 4 + r) * SRS + cm] =
                        (_Float16)(acc[r] * 0.180336880f);  // 0.125*log2e
            }
            bf0 = nb0; bf1 = nb1; act = actn; n0 = n0n;
        }
    }
    __syncthreads();

    // ---------------- phase 2: causal W-segmented rescore (in place) --------
    {
        const float g = ldf(gammas, h, f32);
        const float gl2 = -log1pf(expf(g)) * 1.4426950408889634f; // gamma*log2e
        const int zp = zero_pad[0];
        const int need = (qmax >> 3) + 1;          // lanes of 8 cols needed
        if (need <= 8)
            phase2_impl<3>(s_h, diff, gl2, zp, w, l, q0, b);
        else if (need <= 16)
            phase2_impl<4>(s_h, diff, gl2, zp, w, l, q0, b);
        else if (need <= 32)
            phase2_impl<5>(s_h, diff, gl2, zp, w, l, q0, b);
        else
            phase2_impl<6>(s_h, diff, gl2, zp, w, l, q0, b);
    }
    __syncthreads();

    // ---------------- phase 3: O = P @ V (f16 MFMA), wave = 16-col group ----
    {
        const int g = w;                     // output 16-col group (4 waves)
        const int KS = (qmax >> 5) + 1;
        const _Float16* vb = (const _Float16*)vt +
            ((size_t)(b * 8 + h) * 64 + g * 16 + lq) * 512;
        const _Float16* prow = s_h + lq * SRS;
        f32x4 oacc = {0.f, 0.f, 0.f, 0.f};
        for (int ks = 0; ks < KS; ++ks) {
            const int kb2 = ks * 32 + quad * 8;
            h8 pa = *(const h8*)(prow + kb2 + 8 * (kb2 >> 6));
            h8 vv = *(const h8*)(vb + kb2);
            oacc = __builtin_amdgcn_mfma_f32_16x16x32_f16(pa, vv, oacc, 0, 0, 0);
        }
        const size_t ob = ((size_t)b * 512 + q0 + quad * 4) * 512 + h * 64 + g * 16 + lq;
        #pragma unroll
        for (int r = 0; r < 4; ++r)
            attn[ob + (size_t)r * 512] = f2b(oacc[r]);
    }
}

// ---------------------------------------------------------------------------
extern "C" void kernel_launch(void* const* d_in, const int* in_sizes, int n_in,
                              void* d_out, int out_size, void* d_ws, size_t ws_size,
                              hipStream_t stream) {
    const void* q   = d_in[0];
    const void* k   = d_in[1];
    const void* v   = d_in[2];
    // d_in[3] = mask (tril) == (k<=q), unused
    const int*  zp  = (const int*)d_in[4];
    const void* qde = d_in[5];
    const void* Wk  = d_in[6];
    const void* bk  = d_in[7];
    const void* Wv  = d_in[8];
    const void* bv  = d_in[9];
    const void* Wo  = d_in[10];
    const void* bo  = d_in[11];
    const void* gam = d_in[12];

    const int M = 32 * 512, N = 512, K = 512;
    const int NBIG = M * K;        // 8388608
    const int NW = 512 * 512;      // 262144

    char* ws = (char*)d_ws;
    int* flag = (int*)ws;
    const size_t SZB = (size_t)NBIG * 2;   // 16.8 MB
    const size_t SZW = (size_t)NW * 2;     // 0.5 MB
    u16* cWk  = (u16*)(ws + 1024);
    u16* cWv  = (u16*)(ws + 1024 + SZW);
    u16* cWo  = (u16*)(ws + 1024 + 2 * SZW);
    u16* cq   = (u16*)(ws + 1024 + 3 * SZW);
    u16* ck   = (u16*)(ws + 1024 + 3 * SZW + SZB);
    u16* cv   = (u16*)(ws + 1024 + 3 * SZW + 2 * SZB);
    u16* qh   = (u16*)(ws + 1024 + 3 * SZW + 3 * SZB);
    u16* kh   = (u16*)(ws + 1024 + 3 * SZW + 4 * SZB);
    u16* vt   = (u16*)(ws + 1024 + 3 * SZW + 5 * SZB);   // [B,H,64,S] f16
    u16* attn = (u16*)(ws + 1024 + 3 * SZW + 6 * SZB);   // [B,S,512] bf16

    detect_f32<<<1, 256, 0, stream>>>((const u16*)q, flag);
    cvt3<<<dim3(NW / 2048, 1, 3), 256, 0, stream>>>(Wk, Wv, Wo, cWk, cWv, cWo, NW, flag);

    _Float16* diffb;
    const size_t need_ws = 1024 + 3 * SZW + 8 * SZB;   // +1 slot for fused diff
    if (ws_size >= need_ws) {
        // fused path: diff gets its own slot; one launch for q/k/v cvt + diff
        diffb = (_Float16*)(ws + 1024 + 3 * SZW + 7 * SZB);
        cvt4<<<dim3(NBIG / 2048, 1, 4), 256, 0, stream>>>(
            q, k, v, qde, cq, ck, cv, diffb, NBIG, flag);
        proj3<<<dim3(N / BN, M / BM, 3), 256, 0, stream>>>(
            cq, ck, cv, cWk, cWv, bk, bv, qh, kh, vt, flag, M, N, K);
    } else {
        // fallback: cvt then proj, then diff into dead cq slot
        cvt3<<<dim3(NBIG / 2048, 1, 3), 256, 0, stream>>>(
            q, k, v, cq, ck, cv, NBIG, flag);
        proj3<<<dim3(N / BN, M / BM, 3), 256, 0, stream>>>(
            cq, ck, cv, cWk, cWv, bk, bv, qh, kh, vt, flag, M, N, K);
        diffb = (_Float16*)cq;
        prep_diff<<<dim3(NBIG / 2048), 256, 0, stream>>>(qde, diffb, NBIG, flag);
    }

    akt_attn<<<8192, 256, 0, stream>>>(qh, kh, vt, diffb, gam, zp, flag, attn);
    gemm_out<<<dim3(N / BN, M / BM), 256, 0, stream>>>(attn, cWo, bo, d_out, flag, M, N, K);
}

// Round 8
// 369.799 us; speedup vs baseline: 1.0480x; 1.0022x over previous
//
#include <hip/hip_runtime.h>

typedef unsigned short u16;
typedef __attribute__((ext_vector_type(8))) short short8;
typedef __attribute__((ext_vector_type(8))) _Float16 h8;
typedef __attribute__((ext_vector_type(4))) float f32x4;

// ---- bf16 <-> f32 bit helpers ----
__device__ __forceinline__ float b2f(u16 u) {
    return __uint_as_float(((unsigned int)u) << 16);
}
__device__ __forceinline__ u16 f2b(float f) {
    unsigned int x = __float_as_uint(f);
    return (u16)((x + 0x7FFFu + ((x >> 16) & 1u)) >> 16);   // RNE
}
__device__ __forceinline__ float ldf(const void* p, size_t i, bool f32) {
    return f32 ? ((const float*)p)[i] : b2f(((const u16*)p)[i]);
}
__device__ __forceinline__ void stf(void* p, size_t i, bool f32, float v) {
    if (f32) ((float*)p)[i] = v; else ((u16*)p)[i] = f2b(v);
}
// raw v_exp_f32: computes 2^x in one trans op (no log2e pre-mul)
__device__ __forceinline__ float ex2(float x) {
    float r; asm("v_exp_f32 %0, %1" : "=v"(r) : "v"(x)); return r;
}
__device__ __forceinline__ float rsqf(float x) {
    float r; asm("v_rsq_f32 %0, %1" : "=v"(r) : "v"(x)); return r;
}

// ---- DPP cross-lane add helpers (VALU-speed, vs ~35cy ds_bpermute) --------
template<int CTRL, int RM, bool BC>
__device__ __forceinline__ float dppmov(float x) {
    return __uint_as_float((unsigned)__builtin_amdgcn_update_dpp(
        0, (int)__float_as_uint(x), CTRL, RM, 0xF, BC));
}
// inclusive scan across W=2^LW contiguous lanes (LW in [3,6])
template<int LW>
__device__ __forceinline__ float seg_scan(float x, int ln) {
    if constexpr (LW >= 4) {
        x += dppmov<0x111, 0xF, true>(x);   // row_shr:1
        x += dppmov<0x112, 0xF, true>(x);   // row_shr:2
        x += dppmov<0x114, 0xF, true>(x);   // row_shr:4
        x += dppmov<0x118, 0xF, true>(x);   // row_shr:8  -> 16-wide
        if constexpr (LW >= 5)
            x += dppmov<0x142, 0xA, false>(x);  // row_bcast:15 -> 32-wide
        if constexpr (LW >= 6)
            x += dppmov<0x143, 0xC, false>(x);  // row_bcast:31 -> 64-wide
    } else {
        #pragma unroll
        for (int o = 1; o < (1 << LW); o <<= 1) {
            float u = __shfl_up(x, o, 1 << LW);
            if (ln >= o) x += u;
        }
    }
    return x;
}
// broadcast segment-last lane's value to the whole segment
template<int LW>
__device__ __forceinline__ float seg_bcast_last(float x) {
    if constexpr (LW == 6)
        return __uint_as_float((unsigned)__builtin_amdgcn_readlane(
            (int)__float_as_uint(x), 63));
    else
        return __shfl(x, (1 << LW) - 1, 1 << LW);
}

// async global -> LDS, 16 B per lane (dest = wave-uniform base + lane*16)
__device__ __forceinline__ void ldsld16(const void* g, void* l) {
    __builtin_amdgcn_global_load_lds(
        (const __attribute__((address_space(1))) unsigned int*)g,
        (__attribute__((address_space(3))) unsigned int*)l, 16, 0, 0);
}

// ---------------------------------------------------------------------------
// dtype probe (evidence: flag=1/f32 on this harness; keep robust)
// ---------------------------------------------------------------------------
__global__ void detect_f32(const u16* __restrict__ q, int* __restrict__ flag) {
    __shared__ int cw, cz;
    if (threadIdx.x == 0) { cw = 0; cz = 0; }
    __syncthreads();
    int w = 0, z = 0;
    for (int i = threadIdx.x; i < 4096; i += 256) {
        u16 u = q[i];
        int e = (u >> 7) & 0xFF;
        if (e >= 0xC8) w++;
        if (((i & 1) == 0) && u == 0) z++;
    }
    atomicAdd(&cw, w); atomicAdd(&cz, z);
    __syncthreads();
    if (threadIdx.x == 0) *flag = (cw > 8 || cz > 1024) ? 1 : 0;
}

// ---------------------------------------------------------------------------
// convert 3 tensors -> bf16 ws in one launch. grid (n/2048, 1, 3)
// ---------------------------------------------------------------------------
__global__ __launch_bounds__(256) void cvt3(
    const void* __restrict__ s0, const void* __restrict__ s1,
    const void* __restrict__ s2, u16* __restrict__ d0, u16* __restrict__ d1,
    u16* __restrict__ d2, int n, const int* __restrict__ flag)
{
    const bool f32 = (*flag) != 0;
    const int z = blockIdx.z;
    const void* src = (z == 0) ? s0 : (z == 1) ? s1 : s2;
    u16* dst = (z == 0) ? d0 : (z == 1) ? d1 : d2;
    const int i = (blockIdx.x * 256 + threadIdx.x) * 8;
    if (i >= n) return;
    short8 o;
    if (f32) {
        const float4* s = (const float4*)((const float*)src + i);
        float4 v0 = s[0], v1 = s[1];
        o[0] = (short)f2b(v0.x); o[1] = (short)f2b(v0.y);
        o[2] = (short)f2b(v0.z); o[3] = (short)f2b(v0.w);
        o[4] = (short)f2b(v1.x); o[5] = (short)f2b(v1.y);
        o[6] = (short)f2b(v1.z); o[7] = (short)f2b(v1.w);
    } else {
        o = *(const short8*)((const u16*)src + i);
    }
    *(short8*)(dst + i) = o;
}

// ---------------------------------------------------------------------------
// cvt4: z<3 -> bf16 cvt of q/k/v; z==3 -> diff = exp(sigmoid(qde)) in f16.
// grid (n/2048, 1, 4). Fuses prep_diff into the same memory-bound launch.
// ---------------------------------------------------------------------------
__global__ __launch_bounds__(256) void cvt4(
    const void* __restrict__ s0, const void* __restrict__ s1,
    const void* __restrict__ s2, const void* __restrict__ s3,
    u16* __restrict__ d0, u16* __restrict__ d1, u16* __restrict__ d2,
    _Float16* __restrict__ d3, int n, const int* __restrict__ flag)
{
    const bool f32 = (*flag) != 0;
    const int z = blockIdx.z;
    const int i = (blockIdx.x * 256 + threadIdx.x) * 8;
    if (i >= n) return;
    if (z == 3) {
        float x[8];
        if (f32) {
            const float4* s = (const float4*)((const float*)s3 + i);
            float4 v0 = s[0], v1 = s[1];
            x[0] = v0.x; x[1] = v0.y; x[2] = v0.z; x[3] = v0.w;
            x[4] = v1.x; x[5] = v1.y; x[6] = v1.z; x[7] = v1.w;
        } else {
            short8 v8 = *(const short8*)((const u16*)s3 + i);
            #pragma unroll
            for (int j = 0; j < 8; ++j) x[j] = b2f((u16)v8[j]);
        }
        h8 o;
        #pragma unroll
        for (int j = 0; j < 8; ++j) {
            float sig = __builtin_amdgcn_rcpf(1.f + __expf(-x[j]));
            o[j] = (_Float16)__expf(sig);
        }
        *(h8*)(d3 + i) = o;
        return;
    }
    const void* src = (z == 0) ? s0 : (z == 1) ? s1 : s2;
    u16* dst = (z == 0) ? d0 : (z == 1) ? d1 : d2;
    short8 o;
    if (f32) {
        const float4* s = (const float4*)((const float*)src + i);
        float4 v0 = s[0], v1 = s[1];
        o[0] = (short)f2b(v0.x); o[1] = (short)f2b(v0.y);
        o[2] = (short)f2b(v0.z); o[3] = (short)f2b(v0.w);
        o[4] = (short)f2b(v1.x); o[5] = (short)f2b(v1.y);
        o[6] = (short)f2b(v1.z); o[7] = (short)f2b(v1.w);
    } else {
        o = *(const short8*)((const u16*)src + i);
    }
    *(short8*)(dst + i) = o;
}

// fallback separate diff kernel (used when workspace too small to fuse)
__global__ __launch_bounds__(256) void prep_diff(
    const void* __restrict__ qde, _Float16* __restrict__ diff, int n,
    const int* __restrict__ flag)
{
    const bool f32 = (*flag) != 0;
    const int i = (blockIdx.x * 256 + threadIdx.x) * 8;
    if (i >= n) return;
    float x[8];
    if (f32) {
        const float4* s = (const float4*)((const float*)qde + i);
        float4 v0 = s[0], v1 = s[1];
        x[0] = v0.x; x[1] = v0.y; x[2] = v0.z; x[3] = v0.w;
        x[4] = v1.x; x[5] = v1.y; x[6] = v1.z; x[7] = v1.w;
    } else {
        short8 v8 = *(const short8*)((const u16*)qde + i);
        #pragma unroll
        for (int j = 0; j < 8; ++j) x[j] = b2f((u16)v8[j]);
    }
    h8 o;
    #pragma unroll
    for (int j = 0; j < 8; ++j) {
        float sig = __builtin_amdgcn_rcpf(1.f + __expf(-x[j]));
        o[j] = (_Float16)__expf(sig);
    }
    *(h8*)(diff + i) = o;
}

// ---------------------------------------------------------------------------
// MFMA GEMM core, 2-phase double-buffered (T3/T4-minimal): issue next-tile
// global_load_lds BEFORE computing current tile; wait with COUNTED vmcnt(4)
// so next-stage loads stay in flight across the barrier. HBM latency hides
// under compute+barrier instead of being fully exposed 16x per block.
// mode 0: bf16 head-split; mode 2: f16 head-split^T (V path); mode 1: flat
// ---------------------------------------------------------------------------
#define BM 128
#define BN 128
#define BK 32

__device__ __forceinline__ void gemm_body(
    const u16* __restrict__ A, const u16* __restrict__ W,
    const void* __restrict__ bias, void* __restrict__ dst,
    bool f32, int mode, int bm, int bn, int M, int N, int K)
{
    __shared__ u16 As[2][BM * BK];   // 16 KB
    __shared__ u16 Bs[2][BN * BK];   // 16 KB
    const int t = threadIdx.x;
    const int w = t >> 6, l = t & 63, lq = l & 15, quad = l >> 4;
    const int wr = (w >> 1) * 64, wc = (w & 1) * 64;

    const int whalf = (w & 1) * 64;
    const u16* gsrc = (w < 2) ? A : W;
    const int  gbase = (w < 2) ? bm : bn;

    f32x4 acc[4][4] = {};
    const int NT = K / BK;   // 16

    auto STAGE = [&](int bufid, int k0) {
        u16* lb = (w < 2) ? &As[bufid][0] : &Bs[bufid][0];
        #pragma unroll
        for (int c = 0; c < 4; ++c) {
            const int row = whalf + c * 16 + (l >> 2);
            ldsld16(gsrc + (size_t)(gbase + row) * K + k0 + (l & 3) * 8,
                    lb + row * BK + (l & 3) * 8);
        }
    };

    STAGE(0, 0);                      // prologue: tile 0 in flight
    for (int tt = 0; tt < NT; ++tt) {
        const int cur = tt & 1;
        if (tt + 1 < NT) {
            STAGE(cur ^ 1, (tt + 1) * BK);   // issue next tile (other buffer)
            // wait only the OLDER 4 loads (tile tt); tile tt+1 stays in flight
            asm volatile("s_waitcnt vmcnt(4)" ::: "memory");
        } else {
            asm volatile("s_waitcnt vmcnt(0)" ::: "memory");
        }
        __syncthreads();              // tile tt resident for all waves
        short8 af[4], bf[4];
        #pragma unroll
        for (int i = 0; i < 4; ++i)
            af[i] = *(const short8*)&As[cur][(wr + i * 16 + lq) * BK + quad * 8];
        #pragma unroll
        for (int j = 0; j < 4; ++j)
            bf[j] = *(const short8*)&Bs[cur][(wc + j * 16 + lq) * BK + quad * 8];
        #pragma unroll
        for (int i = 0; i < 4; ++i)
            #pragma unroll
            for (int j = 0; j < 4; ++j)
                acc[i][j] = __builtin_amdgcn_mfma_f32_16x16x32_bf16(
                    af[i], bf[j], acc[i][j], 0, 0, 0);
        __syncthreads();              // buf[cur] free before it's restaged
    }

    #pragma unroll
    for (int j = 0; j < 4; ++j) {
        const int n = bn + wc + j * 16 + lq;
        const float bb = ldf(bias, n, f32);
        #pragma unroll
        for (int i = 0; i < 4; ++i) {
            #pragma unroll
            for (int r = 0; r < 4; ++r) {
                const int m = bm + wr + i * 16 + quad * 4 + r;
                const float vout = acc[i][j][r] + bb;
                if (mode == 0) {
                    const int b = m >> 9, s = m & 511, hh = n >> 6, df = n & 63;
                    ((u16*)dst)[((((size_t)b * 8 + hh) * 512 + s) << 6) + df] = f2b(vout);
                } else if (mode == 2) {
                    const int b = m >> 9, s = m & 511, hh = n >> 6, df = n & 63;
                    _Float16 hv = (_Float16)vout;   // V stored f16 for phase-3 f16 MFMA
                    ((u16*)dst)[((((size_t)b * 8 + hh) * 64 + df) << 9) + s] = *(const u16*)&hv;
                } else {
                    stf(dst, (size_t)m * N + n, f32, vout);
                }
            }
        }
    }
}

__global__ __launch_bounds__(256) void proj3(
    const u16* __restrict__ cq, const u16* __restrict__ ck,
    const u16* __restrict__ cv, const u16* __restrict__ cWk,
    const u16* __restrict__ cWv, const void* __restrict__ bk,
    const void* __restrict__ bv, u16* __restrict__ qh, u16* __restrict__ kh,
    u16* __restrict__ vt, const int* __restrict__ flag, int M, int N, int K)
{
    const int z = blockIdx.z;
    const u16* A = (z == 0) ? cq : (z == 1) ? ck : cv;
    const u16* W = (z < 2) ? cWk : cWv;
    const void* bias = (z < 2) ? bk : bv;
    void* dst = (z == 0) ? (void*)qh : (z == 1) ? (void*)kh : (void*)vt;
    gemm_body(A, W, bias, dst, (*flag) != 0, (z < 2) ? 0 : 2,
              blockIdx.y * BM, blockIdx.x * BN, M, N, K);
}

__global__ __launch_bounds__(256) void gemm_out(
    const u16* __restrict__ A, const u16* __restrict__ W,
    const void* __restrict__ bias, void* __restrict__ dst,
    const int* __restrict__ flag, int M, int N, int K)
{
    gemm_body(A, W, bias, dst, (*flag) != 0, 1,
              blockIdx.y * BM, blockIdx.x * BN, M, N, K);
}

// ---------------------------------------------------------------------------
// Fused AKT attention. Grid 8192, 256 thr (4 waves), 8 blocks/CU.
// Single LDS buffer: phase 1 writes scores; phase 2 rescores IN PLACE
// (rows are wave-exclusive, read-before-write per row); phase 3 reads P,
// each wave owns one 16-col output group over full K (no partial reduce).
// ---------------------------------------------------------------------------
#define QT  16
#define SRS 568   // f16 units; row = 1136 B (16B-aligned)

template<int LW>
__device__ __forceinline__ void phase2_impl(
    _Float16* __restrict__ s_h, const _Float16* __restrict__ diff,
    float gl2, int zp, int w, int l, int q0, int b)
{
    constexpr int W = 1 << LW;        // lanes per row segment
    constexpr int R = 64 >> LW;       // rows per wave-pass
    constexpr int G = 16 / R;         // wave-passes needed (2,4,8,16)
    constexpr int NP = (G + 3) / 4;   // passes per wave (1,1,2,4)
    const int ln = l & (W - 1);
    const int seg = l >> LW;
    const int c0 = ln * 8;
    const int cm = c0 + 8 * (c0 >> 6);

    #pragma unroll
    for (int pp = 0; pp < NP; ++pp) {
        const int p = pp * 4 + w;
        if (G >= 4 || p < G) {
            const int row = p * R + seg;
            const int q = q0 + row;
            const h8 dv = *(const h8*)(diff + ((size_t)b * 512 + q) * 512 + c0);
            const h8 sv16 = *(const h8*)(s_h + row * SRS + cm);
            float sv[8], cs[8];
            float run = 0.f;
            #pragma unroll
            for (int j = 0; j < 8; ++j) {
                float s = (c0 + j <= q) ? (float)sv16[j] : -1e30f;
                sv[j] = s;
                float pe = ex2(s);                 // softmax #1 numerator
                run += pe; cs[j] = run;
            }
            // width-W inclusive scan: DPP adds (VALU) instead of bpermute
            const float incl = seg_scan<LW>(run, ln);
            const float ls   = seg_bcast_last<LW>(incl);   // segment total
            const float t0   = ls - incl + run;            // ls - excl_prefix
            const float grs  = gl2 * rsqf(ls);             // fold 1/sqrt(ls)
            const float qf   = (float)(q - c0);
            // decay rescore + softmax #2 (disttot == 1 identically)
            float f8v[8]; float lf = 0.f;
            #pragma unroll
            for (int j = 0; j < 8; ++j) {
                float suf  = t0 - cs[j];                // suffix sum (unnorm)
                float pos  = qf - (float)j;
                float ms   = fmaxf(suf * pos, 0.f);
                float dist = __builtin_amdgcn_sqrtf(ms);
                // gamma<0 -> arg<=0; low clamp binds: arg >= log2(1e-5)
                float a    = fmaxf(dist * grs * (float)dv[j], -16.609640474f);
                float eff  = ex2(a);
                // masked: sv=-1e30, eff>=1e-5 -> arg<=-1e25 -> f=0
                float f    = ex2(sv[j] * eff);
                f8v[j] = f; lf += f;
            }
            // segment-sum of lf: DPP scan + one broadcast
            if constexpr (LW == 3) {
                lf += __shfl_xor(lf, 4, 64);
                lf += __shfl_xor(lf, 2, 64);
                lf += __shfl_xor(lf, 1, 64);
            } else {
                lf = seg_bcast_last<LW>(seg_scan<LW>(lf, ln));
            }
            float inv2 = __builtin_amdgcn_rcpf(lf);
            if (zp && q == 0) inv2 = 0.f;
            h8 pb;
            #pragma unroll
            for (int j = 0; j < 8; ++j) pb[j] = (_Float16)(f8v[j] * inv2);
            *(h8*)(s_h + row * SRS + cm) = pb;     // in-place: scores -> P
        }
    }
}

__global__ __launch_bounds__(256, 8) void akt_attn(
    const u16* __restrict__ qh, const u16* __restrict__ kh,
    const u16* __restrict__ vt, const _Float16* __restrict__ diff,
    const void* __restrict__ gammas, const int* __restrict__ zero_pad,
    const int* __restrict__ flag, u16* __restrict__ attn)
{
    __shared__ _Float16 s_h[QT * SRS];   // 18176 B (scores, then P in place)

    const int blk = blockIdx.x;
    const int h = blk & 7;               // XCD pin: (b,h) fixed per XCD
    const int i0 = blk >> 3;
    const int qt = 31 - (i0 & 31);       // LPT: heaviest Q-tiles dispatch first
    const int b = i0 >> 5;

    const int q0 = qt * QT;
    const int t = threadIdx.x, w = t >> 6, l = t & 63;
    const int lq = l & 15, quad = l >> 4;
    const bool f32 = (*flag) != 0;
    const size_t bh = ((size_t)b * 8 + h) * 512;
    const int qmax = q0 + QT - 1;

    // ---------------- phase 1: scores = (qh @ kh^T) * 0.125*log2e -> f16 ----
    // 4 waves x 16 cols = 64-col sweeps
    {
        const u16* qb = qh + (bh + q0) * 64;
        short8 af0 = *(const short8*)(qb + lq * 64 +      quad * 8);
        short8 af1 = *(const short8*)(qb + lq * 64 + 32 + quad * 8);
        const u16* kb = kh + bh * 64;
        const int KT = (q0 + QT + 63) >> 6;
        int n0 = w * 16;
        bool act = (n0 <= qmax);
        short8 bf0, bf1;
        if (act) {
            bf0 = *(const short8*)(kb + (size_t)(n0 + lq) * 64 +      quad * 8);
            bf1 = *(const short8*)(kb + (size_t)(n0 + lq) * 64 + 32 + quad * 8);
        }
        for (int kt = 0; kt < KT; ++kt) {
            const int n0n = (kt + 1) * 64 + w * 16;
            const bool actn = (kt + 1 < KT) && (n0n <= qmax);
            short8 nb0, nb1;
            if (actn) {
                nb0 = *(const short8*)(kb + (size_t)(n0n + lq) * 64 +      quad * 8);
                nb1 = *(const short8*)(kb + (size_t)(n0n + lq) * 64 + 32 + quad * 8);
            }
            if (act) {
                f32x4 acc = {0.f, 0.f, 0.f, 0.f};
                acc = __builtin_amdgcn_mfma_f32_16x16x32_bf16(af0, bf0, acc, 0, 0, 0);
                acc = __builtin_amdgcn_mfma_f32_16x16x32_bf16(af1, bf1, acc, 0, 0, 0);
                const int cm = n0 + lq + 8 * (n0 >> 6);
                #pragma unroll
                for (int r = 0; r < 4; ++r)
                    s_h[(quad * 4 + r) * SRS + cm] =
                        (_Float16)(acc[r] * 0.180336880f);  // 0.125*log2e
            }
            bf0 = nb0; bf1 = nb1; act = actn; n0 = n0n;
        }
    }
    __syncthreads();

    // ---------------- phase 2: causal W-segmented rescore (in place) --------
    {
        const float g = ldf(gammas, h, f32);
        const float gl2 = -log1pf(expf(g)) * 1.4426950408889634f; // gamma*log2e
        const int zp = zero_pad[0];
        const int need = (qmax >> 3) + 1;          // lanes of 8 cols needed
        if (need <= 8)
            phase2_impl<3>(s_h, diff, gl2, zp, w, l, q0, b);
        else if (need <= 16)
            phase2_impl<4>(s_h, diff, gl2, zp, w, l, q0, b);
        else if (need <= 32)
            phase2_impl<5>(s_h, diff, gl2, zp, w, l, q0, b);
        else
            phase2_impl<6>(s_h, diff, gl2, zp, w, l, q0, b);
    }
    __syncthreads();

    // ---------------- phase 3: O = P @ V (f16 MFMA), wave = 16-col group ----
    {
        const int g = w;                     // output 16-col group (4 waves)
        const int KS = (qmax >> 5) + 1;
        const _Float16* vb = (const _Float16*)vt +
            ((size_t)(b * 8 + h) * 64 + g * 16 + lq) * 512;
        const _Float16* prow = s_h + lq * SRS;
        f32x4 oacc = {0.f, 0.f, 0.f, 0.f};
        for (int ks = 0; ks < KS; ++ks) {
            const int kb2 = ks * 32 + quad * 8;
            h8 pa = *(const h8*)(prow + kb2 + 8 * (kb2 >> 6));
            h8 vv = *(const h8*)(vb + kb2);
            oacc = __builtin_amdgcn_mfma_f32_16x16x32_f16(pa, vv, oacc, 0, 0, 0);
        }
        const size_t ob = ((size_t)b * 512 + q0 + quad * 4) * 512 + h * 64 + g * 16 + lq;
        #pragma unroll
        for (int r = 0; r < 4; ++r)
            attn[ob + (size_t)r * 512] = f2b(oacc[r]);
    }
}

// ---------------------------------------------------------------------------
extern "C" void kernel_launch(void* const* d_in, const int* in_sizes, int n_in,
                              void* d_out, int out_size, void* d_ws, size_t ws_size,
                              hipStream_t stream) {
    const void* q   = d_in[0];
    const void* k   = d_in[1];
    const void* v   = d_in[2];
    // d_in[3] = mask (tril) == (k<=q), unused
    const int*  zp  = (const int*)d_in[4];
    const void* qde = d_in[5];
    const void* Wk  = d_in[6];
    const void* bk  = d_in[7];
    const void* Wv  = d_in[8];
    const void* bv  = d_in[9];
    const void* Wo  = d_in[10];
    const void* bo  = d_in[11];
    const void* gam = d_in[12];

    const int M = 32 * 512, N = 512, K = 512;
    const int NBIG = M * K;        // 8388608
    const int NW = 512 * 512;      // 262144

    char* ws = (char*)d_ws;
    int* flag = (int*)ws;
    const size_t SZB = (size_t)NBIG * 2;   // 16.8 MB
    const size_t SZW = (size_t)NW * 2;     // 0.5 MB
    u16* cWk  = (u16*)(ws + 1024);
    u16* cWv  = (u16*)(ws + 1024 + SZW);
    u16* cWo  = (u16*)(ws + 1024 + 2 * SZW);
    u16* cq   = (u16*)(ws + 1024 + 3 * SZW);
    u16* ck   = (u16*)(ws + 1024 + 3 * SZW + SZB);
    u16* cv   = (u16*)(ws + 1024 + 3 * SZW + 2 * SZB);
    u16* qh   = (u16*)(ws + 1024 + 3 * SZW + 3 * SZB);
    u16* kh   = (u16*)(ws + 1024 + 3 * SZW + 4 * SZB);
    u16* vt   = (u16*)(ws + 1024 + 3 * SZW + 5 * SZB);   // [B,H,64,S] f16
    u16* attn = (u16*)(ws + 1024 + 3 * SZW + 6 * SZB);   // [B,S,512] bf16

    detect_f32<<<1, 256, 0, stream>>>((const u16*)q, flag);
    cvt3<<<dim3(NW / 2048, 1, 3), 256, 0, stream>>>(Wk, Wv, Wo, cWk, cWv, cWo, NW, flag);

    _Float16* diffb;
    const size_t need_ws = 1024 + 3 * SZW + 8 * SZB;   // +1 slot for fused diff
    if (ws_size >= need_ws) {
        // fused path: diff gets its own slot; one launch for q/k/v cvt + diff
        diffb = (_Float16*)(ws + 1024 + 3 * SZW + 7 * SZB);
        cvt4<<<dim3(NBIG / 2048, 1, 4), 256, 0, stream>>>(
            q, k, v, qde, cq, ck, cv, diffb, NBIG, flag);
        proj3<<<dim3(N / BN, M / BM, 3), 256, 0, stream>>>(
            cq, ck, cv, cWk, cWv, bk, bv, qh, kh, vt, flag, M, N, K);
    } else {
        // fallback: cvt then proj, then diff into dead cq slot
        cvt3<<<dim3(NBIG / 2048, 1, 3), 256, 0, stream>>>(
            q, k, v, cq, ck, cv, NBIG, flag);
        proj3<<<dim3(N / BN, M / BM, 3), 256, 0, stream>>>(
            cq, ck, cv, cWk, cWv, bk, bv, qh, kh, vt, flag, M, N, K);
        diffb = (_Float16*)cq;
        prep_diff<<<dim3(NBIG / 2048), 256, 0, stream>>>(qde, diffb, NBIG, flag);
    }

    akt_attn<<<8192, 256, 0, stream>>>(qh, kh, vt, diffb, gam, zp, flag, attn);
    gemm_out<<<dim3(N / BN, M / BM), 256, 0, stream>>>(attn, cWo, bo, d_out, flag, M, N, K);
}